// Round 10
// baseline (428.498 us; speedup 1.0000x reference)
//
#include <hip/hip_runtime.h>
#include <hip/hip_bf16.h>

#define N_FEAT 7
#define HIDDEN 128
#define N_CLASSES 2
#define N_GRAPHS 64
#define SCAN_TILE 1024
#define QBLOCKS 1024

// ---------------------------------------------------------------- zero init: deg[N] + alphaT[N*64] + q[64*128]
__global__ void k_zero(int* __restrict__ deg, float* __restrict__ alphaT,
                       float* __restrict__ q, int n) {
    int i = blockIdx.x * blockDim.x + threadIdx.x;
    if (i < n) deg[i] = 0;
    if (i < n * N_GRAPHS) alphaT[i] = 0.f;
    if (i < N_GRAPHS * HIDDEN) q[i] = 0.f;
}

// ---------------------------------------------------------------- degree count (4 edges/thread)
__global__ void k_count(const int* __restrict__ dst, int* __restrict__ deg, int E) {
    int e4 = (blockIdx.x * blockDim.x + threadIdx.x) << 2;
    if (e4 + 4 <= E) {
        int4 d = *(const int4*)&dst[e4];
        atomicAdd(&deg[d.x], 1);
        atomicAdd(&deg[d.y], 1);
        atomicAdd(&deg[d.z], 1);
        atomicAdd(&deg[d.w], 1);
    } else {
        for (int e = e4; e < E; ++e) atomicAdd(&deg[dst[e]], 1);
    }
}

// ---------------------------------------------------------------- scan phase A
__global__ __launch_bounds__(1024) void k_scan_a(const int* __restrict__ deg,
                                                 int* __restrict__ bsum, int n) {
    __shared__ int s[SCAN_TILE];
    int tid = threadIdx.x;
    int i = blockIdx.x * SCAN_TILE + tid;
    s[tid] = (i < n) ? deg[i] : 0;
    __syncthreads();
#pragma unroll
    for (int off = 512; off > 0; off >>= 1) {
        if (tid < off) s[tid] += s[tid + off];
        __syncthreads();
    }
    if (tid == 0) bsum[blockIdx.x] = s[0];
}

// ---------------------------------------------------------------- scan phase B (1 block)
__global__ __launch_bounds__(1024) void k_scan_b(const int* __restrict__ bsum,
                                                 int* __restrict__ boff,
                                                 int* __restrict__ start, int B, int n) {
    __shared__ int s[SCAN_TILE];
    int tid = threadIdx.x;
    int v = (tid < B) ? bsum[tid] : 0;
    s[tid] = v;
    __syncthreads();
    for (int off = 1; off < SCAN_TILE; off <<= 1) {
        int t = (tid >= off) ? s[tid - off] : 0;
        __syncthreads();
        s[tid] += t;
        __syncthreads();
    }
    if (tid < B) boff[tid] = s[tid] - v;
    if (tid == B - 1) start[n] = s[tid];
}

// ---------------------------------------------------------------- scan phase C
__global__ __launch_bounds__(1024) void k_scan_c(const int* __restrict__ deg,
                                                 const int* __restrict__ boff,
                                                 int* __restrict__ start,
                                                 int* __restrict__ cursor,
                                                 float* __restrict__ dinv, int n) {
    __shared__ int s[SCAN_TILE];
    int tid = threadIdx.x;
    int i = blockIdx.x * SCAN_TILE + tid;
    int v = (i < n) ? deg[i] : 0;
    s[tid] = v;
    __syncthreads();
    for (int off = 1; off < SCAN_TILE; off <<= 1) {
        int t = (tid >= off) ? s[tid - off] : 0;
        __syncthreads();
        s[tid] += t;
        __syncthreads();
    }
    if (i < n) {
        int ex = boff[blockIdx.x] + s[tid] - v;
        start[i] = ex;
        cursor[i] = ex;
        dinv[i] = rsqrtf((float)(v + 1));
    }
}

// ---------------------------------------------------------------- CSR fill + alphaT edge scatter:
// csr_src[pos]=src ; alphaT[src][batch[dst]] += dinv[dst]
__global__ void k_fill(const int* __restrict__ src, const int* __restrict__ dst,
                       const int* __restrict__ batch, const float* __restrict__ dinv,
                       int* __restrict__ cursor, int* __restrict__ csr_src,
                       float* __restrict__ alphaT, int E) {
    int e4 = (blockIdx.x * blockDim.x + threadIdx.x) << 2;
    if (e4 + 4 <= E) {
        int4 s = *(const int4*)&src[e4];
        int4 d = *(const int4*)&dst[e4];
        csr_src[atomicAdd(&cursor[d.x], 1)] = s.x;
        csr_src[atomicAdd(&cursor[d.y], 1)] = s.y;
        csr_src[atomicAdd(&cursor[d.z], 1)] = s.z;
        csr_src[atomicAdd(&cursor[d.w], 1)] = s.w;
        atomicAdd(&alphaT[(size_t)s.x * N_GRAPHS + batch[d.x]], dinv[d.x]);
        atomicAdd(&alphaT[(size_t)s.y * N_GRAPHS + batch[d.y]], dinv[d.y]);
        atomicAdd(&alphaT[(size_t)s.z * N_GRAPHS + batch[d.z]], dinv[d.z]);
        atomicAdd(&alphaT[(size_t)s.w * N_GRAPHS + batch[d.w]], dinv[d.w]);
    } else {
        for (int e = e4; e < E; ++e) {
            int s = src[e], d = dst[e];
            csr_src[atomicAdd(&cursor[d], 1)] = s;
            atomicAdd(&alphaT[(size_t)s * N_GRAPHS + batch[d]], dinv[d]);
        }
    }
}

// ---------------------------------------------------------------- graph boundaries
__global__ void k_bounds(const int* __restrict__ batch, int* __restrict__ goff, int n) {
    int g = threadIdx.x;
    if (g > N_GRAPHS) return;
    int lo = 0, hi = n;
    while (lo < hi) {
        int m = (lo + hi) >> 1;
        if (batch[m] < g) lo = m + 1; else hi = m;
    }
    goff[g] = lo;
}

// ---------------------------------------------------------------- prep: xp = dinv*x (pad 8) ; alphaT self term
__global__ void k_prep(const float* __restrict__ x, const float* __restrict__ dinv,
                       const int* __restrict__ batch, float* __restrict__ xp,
                       float* __restrict__ alphaT, int n) {
    int t = blockIdx.x * blockDim.x + threadIdx.x;
    int i = t >> 3, j = t & 7;
    if (i >= n) return;
    xp[t] = (j < N_FEAT) ? dinv[i] * x[i * N_FEAT + j] : 0.f;
    if (j == 0) alphaT[(size_t)i * N_GRAPHS + batch[i]] += dinv[i];  // after k_fill, unique per i
}

// ---------------------------------------------------------------- layer-1 aggregation on 7-dim (L2-resident)
__global__ __launch_bounds__(256) void k_agg7(const float* __restrict__ xp,
                                              float* __restrict__ ax,
                                              const int* __restrict__ start,
                                              const int* __restrict__ csr_src,
                                              const float* __restrict__ dinv, int nnodes) {
    int t = blockIdx.x * blockDim.x + threadIdx.x;
    int g = t >> 3, j = t & 7;
    if (g >= nnodes) return;
    float acc = xp[(size_t)g * 8 + j];
    int e0 = start[g], e1 = start[g + 1];
    int e = e0;
    for (; e + 4 <= e1; e += 4) {
        int s0 = csr_src[e + 0], s1 = csr_src[e + 1];
        int s2 = csr_src[e + 2], s3 = csr_src[e + 3];
        acc += xp[(size_t)s0 * 8 + j] + xp[(size_t)s1 * 8 + j]
             + xp[(size_t)s2 * 8 + j] + xp[(size_t)s3 * 8 + j];
    }
    for (; e < e1; ++e) acc += xp[(size_t)csr_src[e] * 8 + j];
    ax[(size_t)g * 8 + j] = dinv[g] * acc;
}

// ---------------------------------------------------------------- layer-1 transform: h1 = relu(ax @ W1 + b1)
__global__ __launch_bounds__(256) void k_gemm7(const float* __restrict__ AX,
                                               const float* __restrict__ W1,
                                               const float* __restrict__ b1,
                                               float* __restrict__ h1, int n) {
    __shared__ float w[N_FEAT * HIDDEN];
    __shared__ float bs[HIDDEN];
    int tid = threadIdx.x;
    for (int i = tid; i < N_FEAT * HIDDEN; i += 256) w[i] = W1[i];
    if (tid < HIDDEN) bs[tid] = b1[tid];
    __syncthreads();
    int row = blockIdx.x * 2 + (tid >> 7);
    int col = tid & 127;
    if (row >= n) return;
    float acc = bs[col];
#pragma unroll
    for (int k = 0; k < N_FEAT; ++k)
        acc += AX[(size_t)row * 8 + k] * w[k * HIDDEN + col];
    h1[(size_t)row * HIDDEN + col] = fmaxf(acc, 0.f);
}

// ---------------------------------------------------------------- dense fp32 GEMM with dinv pre-scale: Ts = dinv*(A@W)
__global__ __launch_bounds__(256) void k_gemm128(const float* __restrict__ A,
                                                 const float* __restrict__ W,
                                                 const float* __restrict__ dinv,
                                                 float* __restrict__ Ts, int nrows) {
    __shared__ float as[16][68];
    __shared__ float ws[16][132];
    int row0 = blockIdx.x * 64;
    int tid = threadIdx.x;
    int tr = tid >> 4;
    int tc = tid & 15;
    float acc[4][8] = {};
    for (int k0 = 0; k0 < 128; k0 += 16) {
        {
            int r = tid >> 2;
            int ko = (tid & 3) << 2;
            float4 av = make_float4(0.f, 0.f, 0.f, 0.f);
            if (row0 + r < nrows)
                av = *(const float4*)&A[(size_t)(row0 + r) * 128 + k0 + ko];
            as[ko + 0][r] = av.x; as[ko + 1][r] = av.y;
            as[ko + 2][r] = av.z; as[ko + 3][r] = av.w;
        }
        {
            int wk = tid >> 4;
            int wc = (tid & 15) << 2;
            const float* wp = &W[(size_t)(k0 + wk) * 128 + wc];
            *(float4*)&ws[wk][wc]      = *(const float4*)(wp);
            *(float4*)&ws[wk][wc + 64] = *(const float4*)(wp + 64);
        }
        __syncthreads();
#pragma unroll
        for (int kk = 0; kk < 16; ++kk) {
            float a[4], b[8];
            *(float4*)&a[0] = *(const float4*)&as[kk][tr * 4];
            *(float4*)&b[0] = *(const float4*)&ws[kk][tc * 4];
            *(float4*)&b[4] = *(const float4*)&ws[kk][64 + tc * 4];
#pragma unroll
            for (int i = 0; i < 4; ++i)
#pragma unroll
                for (int j = 0; j < 8; ++j)
                    acc[i][j] += a[i] * b[j];
        }
        __syncthreads();
    }
#pragma unroll
    for (int i = 0; i < 4; ++i) {
        int rr = row0 + tr * 4 + i;
        if (rr < nrows) {
            float sc = dinv[rr];
            float* dstp = &Ts[(size_t)rr * 128];
            *(float4*)(dstp + tc * 4)      = make_float4(sc * acc[i][0], sc * acc[i][1], sc * acc[i][2], sc * acc[i][3]);
            *(float4*)(dstp + 64 + tc * 4) = make_float4(sc * acc[i][4], sc * acc[i][5], sc * acc[i][6], sc * acc[i][7]);
        }
    }
}

// ---------------------------------------------------------------- aggregation on pre-scaled Ts (layer 2 only):
__global__ __launch_bounds__(256) void k_agg(const float* __restrict__ Ts, float* __restrict__ H,
                                             const int* __restrict__ start,
                                             const int* __restrict__ csr_src,
                                             const float* __restrict__ dinv,
                                             const float* __restrict__ bias,
                                             int relu, int nnodes) {
    int g = (blockIdx.x * blockDim.x + threadIdx.x) >> 5;
    int lane = threadIdx.x & 31;
    if (g >= nnodes) return;
    const size_t loff = (size_t)lane * 4;
    float4 v = *(const float4*)&Ts[(size_t)g * 128 + loff];
    float ax = v.x, ay = v.y, az = v.z, aw = v.w;
    int e0 = start[g], e1 = start[g + 1];
    int e = e0;
    for (; e + 8 <= e1; e += 8) {
        int s[8];
        float4 u[8];
#pragma unroll
        for (int j = 0; j < 8; ++j) s[j] = csr_src[e + j];
#pragma unroll
        for (int j = 0; j < 8; ++j) u[j] = *(const float4*)&Ts[(size_t)s[j] * 128 + loff];
#pragma unroll
        for (int j = 0; j < 8; ++j) {
            ax += u[j].x; ay += u[j].y; az += u[j].z; aw += u[j].w;
        }
    }
    if (e + 4 <= e1) {
        int s[4];
        float4 u[4];
#pragma unroll
        for (int j = 0; j < 4; ++j) s[j] = csr_src[e + j];
#pragma unroll
        for (int j = 0; j < 4; ++j) u[j] = *(const float4*)&Ts[(size_t)s[j] * 128 + loff];
#pragma unroll
        for (int j = 0; j < 4; ++j) {
            ax += u[j].x; ay += u[j].y; az += u[j].z; aw += u[j].w;
        }
        e += 4;
    }
    for (; e < e1; ++e) {
        float4 u = *(const float4*)&Ts[(size_t)csr_src[e] * 128 + loff];
        ax += u.x; ay += u.y; az += u.z; aw += u.w;
    }
    float di = dinv[g];
    float4 b = *(const float4*)&bias[loff];
    ax = di * ax + b.x; ay = di * ay + b.y;
    az = di * az + b.z; aw = di * aw + b.w;
    if (relu) {
        ax = fmaxf(ax, 0.f); ay = fmaxf(ay, 0.f);
        az = fmaxf(az, 0.f); aw = fmaxf(aw, 0.f);
    }
    *(float4*)&H[(size_t)g * 128 + loff] = make_float4(ax, ay, az, aw);
}

// ---------------------------------------------------------------- q stage v2: 1024 blocks, unroll-2, direct atomics
// q[g][d] += sum_{s in chunk} alphaT[s][g] * dinv[s] * H2[s][d]
__global__ __launch_bounds__(256) void k_qstage(const float* __restrict__ H,
                                                const float* __restrict__ alphaT,
                                                const float* __restrict__ dinv,
                                                float* __restrict__ q, int n) {
    int gg = threadIdx.x >> 5;     // graph octet 0..7
    int lane = threadIdx.x & 31;   // dims lane*4..+3
    int per = (n + gridDim.x - 1) / gridDim.x;
    int n0 = blockIdx.x * per;
    int n1 = min(n, n0 + per);
    float4 acc[8];
#pragma unroll
    for (int k = 0; k < 8; ++k) acc[k] = make_float4(0.f, 0.f, 0.f, 0.f);
    int s = n0;
    for (; s + 2 <= n1; s += 2) {
        float ds0 = dinv[s], ds1 = dinv[s + 1];
        float4 h0 = *(const float4*)&H[(size_t)s * 128 + lane * 4];
        float4 h1 = *(const float4*)&H[(size_t)(s + 1) * 128 + lane * 4];
        float4 a0lo = *(const float4*)&alphaT[(size_t)s * N_GRAPHS + gg * 8];
        float4 a0hi = *(const float4*)&alphaT[(size_t)s * N_GRAPHS + gg * 8 + 4];
        float4 a1lo = *(const float4*)&alphaT[(size_t)(s + 1) * N_GRAPHS + gg * 8];
        float4 a1hi = *(const float4*)&alphaT[(size_t)(s + 1) * N_GRAPHS + gg * 8 + 4];
        h0.x *= ds0; h0.y *= ds0; h0.z *= ds0; h0.w *= ds0;
        h1.x *= ds1; h1.y *= ds1; h1.z *= ds1; h1.w *= ds1;
        const float a0[8] = {a0lo.x, a0lo.y, a0lo.z, a0lo.w, a0hi.x, a0hi.y, a0hi.z, a0hi.w};
        const float a1[8] = {a1lo.x, a1lo.y, a1lo.z, a1lo.w, a1hi.x, a1hi.y, a1hi.z, a1hi.w};
#pragma unroll
        for (int k = 0; k < 8; ++k) {
            acc[k].x += a0[k] * h0.x + a1[k] * h1.x;
            acc[k].y += a0[k] * h0.y + a1[k] * h1.y;
            acc[k].z += a0[k] * h0.z + a1[k] * h1.z;
            acc[k].w += a0[k] * h0.w + a1[k] * h1.w;
        }
    }
    for (; s < n1; ++s) {
        float ds = dinv[s];
        float4 h = *(const float4*)&H[(size_t)s * 128 + lane * 4];
        h.x *= ds; h.y *= ds; h.z *= ds; h.w *= ds;
        float4 alo = *(const float4*)&alphaT[(size_t)s * N_GRAPHS + gg * 8];
        float4 ahi = *(const float4*)&alphaT[(size_t)s * N_GRAPHS + gg * 8 + 4];
        const float a[8] = {alo.x, alo.y, alo.z, alo.w, ahi.x, ahi.y, ahi.z, ahi.w};
#pragma unroll
        for (int k = 0; k < 8; ++k) {
            acc[k].x += a[k] * h.x; acc[k].y += a[k] * h.y;
            acc[k].z += a[k] * h.z; acc[k].w += a[k] * h.w;
        }
    }
    if (n0 >= n1) return;
#pragma unroll
    for (int k = 0; k < 8; ++k) {
        float* qp = &q[(size_t)(gg * 8 + k) * HIDDEN + lane * 4];
        atomicAdd(qp + 0, acc[k].x);
        atomicAdd(qp + 1, acc[k].y);
        atomicAdd(qp + 2, acc[k].z);
        atomicAdd(qp + 3, acc[k].w);
    }
}

// ---------------------------------------------------------------- Wc = W3 @ Wl [128,2]; bc = b3 @ Wl + bl
__global__ void k_wc(const float* __restrict__ W3, const float* __restrict__ Wl,
                     const float* __restrict__ b3, const float* __restrict__ bl,
                     float* __restrict__ Wc, float* __restrict__ bc) {
    int t = threadIdx.x;               // 256 threads: k=t>>1 (0..127), c=t&1
    int k = t >> 1, c = t & 1;
    float acc = 0.f;
#pragma unroll 8
    for (int j = 0; j < HIDDEN; ++j) acc += W3[k * HIDDEN + j] * Wl[j * N_CLASSES + c];
    Wc[k * N_CLASSES + c] = acc;
    if (k == 0) {
        float b = bl[c];
        for (int j = 0; j < HIDDEN; ++j) b += b3[j] * Wl[j * N_CLASSES + c];
        bc[c] = b;
    }
}

// ---------------------------------------------------------------- final: out[g][c] = (q[g]@Wc)[c]/cnt + bc[c]
__global__ void k_final2(const float* __restrict__ q, const float* __restrict__ Wc,
                         const float* __restrict__ bc, const int* __restrict__ goff,
                         float* __restrict__ out) {
    int t = threadIdx.x;               // 128 threads
    int g = t >> 1, c = t & 1;
    float inv = 1.0f / (float)max(goff[g + 1] - goff[g], 1);
    float acc = 0.f;
#pragma unroll 8
    for (int k = 0; k < HIDDEN; ++k) acc += q[g * HIDDEN + k] * Wc[k * N_CLASSES + c];
    out[g * N_CLASSES + c] = acc * inv + bc[c];
}

// ================================================================ launch
extern "C" void kernel_launch(void* const* d_in, const int* in_sizes, int n_in,
                              void* d_out, int out_size, void* d_ws, size_t ws_size,
                              hipStream_t stream) {
    const float* x    = (const float*)d_in[0];
    const int*   ei   = (const int*)d_in[1];
    const int*   batch= (const int*)d_in[2];
    const float* W1   = (const float*)d_in[3];
    const float* b1   = (const float*)d_in[4];
    const float* W2   = (const float*)d_in[5];
    const float* b2   = (const float*)d_in[6];
    const float* W3   = (const float*)d_in[7];
    const float* b3   = (const float*)d_in[8];
    const float* Wl   = (const float*)d_in[9];
    const float* bl   = (const float*)d_in[10];
    float* out = (float*)d_out;

    const int N = in_sizes[0] / N_FEAT;        // 40000
    const int E = in_sizes[1] / 2;             // 640000
    const int* e_src = ei;
    const int* e_dst = ei + E;
    const int B = (N + SCAN_TILE - 1) / SCAN_TILE;

    // workspace carve-out (256B aligned)
    char* ws = (char*)d_ws;
    auto carve = [&](size_t bytes) -> char* {
        char* p = ws;
        ws += (bytes + 255) & ~(size_t)255;
        return p;
    };
    float* T        = (float*)carve((size_t)N * HIDDEN * 4);   // Ts (layer-2 pre-scaled transform)
    float* H        = (float*)carve((size_t)N * HIDDEN * 4);   // h1 then h2
    float* xp       = (float*)carve((size_t)N * 8 * 4);
    float* ax       = (float*)carve((size_t)N * 8 * 4);
    int*   deg      = (int*)  carve((size_t)N * 4);
    int*   start    = (int*)  carve((size_t)(N + 1) * 4);
    int*   cursor   = (int*)  carve((size_t)N * 4);
    float* dinv     = (float*)carve((size_t)N * 4);
    int*   csr_src  = (int*)  carve((size_t)E * 4);
    float* alphaT   = (float*)carve((size_t)N * N_GRAPHS * 4); // 10.2 MB
    float* q        = (float*)carve((size_t)N_GRAPHS * HIDDEN * 4);
    float* Wc       = (float*)carve((size_t)HIDDEN * N_CLASSES * 4);
    float* bc       = (float*)carve((size_t)N_CLASSES * 4);
    int*   goff     = (int*)  carve((size_t)(N_GRAPHS + 1) * 4);
    int*   bsum     = (int*)  carve((size_t)B * 4);
    int*   boff     = (int*)  carve((size_t)B * 4);
    if ((size_t)(ws - (char*)d_ws) > ws_size) return;

    // --- CSR + alphaT build + graph bounds ---
    k_zero  <<<(N * N_GRAPHS + 255) / 256, 256, 0, stream>>>(deg, alphaT, q, N);
    k_count <<<(E / 4 + 255) / 256, 256, 0, stream>>>(e_dst, deg, E);
    k_scan_a<<<B, 1024, 0, stream>>>(deg, bsum, N);
    k_scan_b<<<1, 1024, 0, stream>>>(bsum, boff, start, B, N);
    k_scan_c<<<B, 1024, 0, stream>>>(deg, boff, start, cursor, dinv, N);
    k_fill  <<<(E / 4 + 255) / 256, 256, 0, stream>>>(e_src, e_dst, batch, dinv, cursor, csr_src, alphaT, E);
    k_bounds<<<1, 128, 0, stream>>>(batch, goff, N);

    const int aggBlocks  = (N * 32 + 255) / 256;
    const int gemmBlocks = (N + 63) / 64;

    // --- layer 1: aggregate 7-dim, then transform ---
    k_prep <<<(N * 8 + 255) / 256, 256, 0, stream>>>(x, dinv, batch, xp, alphaT, N);
    k_agg7 <<<(N * 8 + 255) / 256, 256, 0, stream>>>(xp, ax, start, csr_src, dinv, N);
    k_gemm7<<<(N + 1) / 2, 256, 0, stream>>>(ax, W1, b1, H, N);   // H = h1
    // --- layer 2 ---
    k_gemm128<<<gemmBlocks, 256, 0, stream>>>(H, W2, dinv, T, N); // T = dinv*(h1@W2)
    k_agg    <<<aggBlocks, 256, 0, stream>>>(T, H, start, csr_src, dinv, b2, 1, N);  // H = h2
    // --- layer 3 + pool + classifier, collapsed by linearity ---
    k_qstage<<<QBLOCKS, 256, 0, stream>>>(H, alphaT, dinv, q, N);
    k_wc    <<<1, 256, 0, stream>>>(W3, Wl, b3, bl, Wc, bc);
    k_final2<<<1, 128, 0, stream>>>(q, Wc, bc, goff, out);
}

// Round 11
// 278.839 us; speedup vs baseline: 1.5367x; 1.5367x over previous
//
#include <hip/hip_runtime.h>
#include <hip/hip_bf16.h>

#define N_FEAT 7
#define HIDDEN 128
#define N_CLASSES 2
#define N_GRAPHS 64
#define SCAN_TILE 1024
#define QBLOCKS 512   // qpart (64*128 floats per block) aliases dead Ts buffer: 512*32KB = 16.8MB < 20.5MB

// ---------------------------------------------------------------- zero init: deg[N] + alphaT[N*64]
__global__ void k_zero(int* __restrict__ deg, float* __restrict__ alphaT, int n) {
    int i = blockIdx.x * blockDim.x + threadIdx.x;
    if (i < n) deg[i] = 0;
    if (i < n * N_GRAPHS) alphaT[i] = 0.f;
}

// ---------------------------------------------------------------- degree count (4 edges/thread)
__global__ void k_count(const int* __restrict__ dst, int* __restrict__ deg, int E) {
    int e4 = (blockIdx.x * blockDim.x + threadIdx.x) << 2;
    if (e4 + 4 <= E) {
        int4 d = *(const int4*)&dst[e4];
        atomicAdd(&deg[d.x], 1);
        atomicAdd(&deg[d.y], 1);
        atomicAdd(&deg[d.z], 1);
        atomicAdd(&deg[d.w], 1);
    } else {
        for (int e = e4; e < E; ++e) atomicAdd(&deg[dst[e]], 1);
    }
}

// ---------------------------------------------------------------- scan phase A
__global__ __launch_bounds__(1024) void k_scan_a(const int* __restrict__ deg,
                                                 int* __restrict__ bsum, int n) {
    __shared__ int s[SCAN_TILE];
    int tid = threadIdx.x;
    int i = blockIdx.x * SCAN_TILE + tid;
    s[tid] = (i < n) ? deg[i] : 0;
    __syncthreads();
#pragma unroll
    for (int off = 512; off > 0; off >>= 1) {
        if (tid < off) s[tid] += s[tid + off];
        __syncthreads();
    }
    if (tid == 0) bsum[blockIdx.x] = s[0];
}

// ---------------------------------------------------------------- scan phase B (1 block)
__global__ __launch_bounds__(1024) void k_scan_b(const int* __restrict__ bsum,
                                                 int* __restrict__ boff,
                                                 int* __restrict__ start, int B, int n) {
    __shared__ int s[SCAN_TILE];
    int tid = threadIdx.x;
    int v = (tid < B) ? bsum[tid] : 0;
    s[tid] = v;
    __syncthreads();
    for (int off = 1; off < SCAN_TILE; off <<= 1) {
        int t = (tid >= off) ? s[tid - off] : 0;
        __syncthreads();
        s[tid] += t;
        __syncthreads();
    }
    if (tid < B) boff[tid] = s[tid] - v;
    if (tid == B - 1) start[n] = s[tid];
}

// ---------------------------------------------------------------- scan phase C
__global__ __launch_bounds__(1024) void k_scan_c(const int* __restrict__ deg,
                                                 const int* __restrict__ boff,
                                                 int* __restrict__ start,
                                                 int* __restrict__ cursor,
                                                 float* __restrict__ dinv, int n) {
    __shared__ int s[SCAN_TILE];
    int tid = threadIdx.x;
    int i = blockIdx.x * SCAN_TILE + tid;
    int v = (i < n) ? deg[i] : 0;
    s[tid] = v;
    __syncthreads();
    for (int off = 1; off < SCAN_TILE; off <<= 1) {
        int t = (tid >= off) ? s[tid - off] : 0;
        __syncthreads();
        s[tid] += t;
        __syncthreads();
    }
    if (i < n) {
        int ex = boff[blockIdx.x] + s[tid] - v;
        start[i] = ex;
        cursor[i] = ex;
        dinv[i] = rsqrtf((float)(v + 1));
    }
}

// ---------------------------------------------------------------- CSR fill + alphaT edge scatter:
// csr_src[pos]=src ; alphaT[src][batch[dst]] += dinv[dst]
__global__ void k_fill(const int* __restrict__ src, const int* __restrict__ dst,
                       const int* __restrict__ batch, const float* __restrict__ dinv,
                       int* __restrict__ cursor, int* __restrict__ csr_src,
                       float* __restrict__ alphaT, int E) {
    int e4 = (blockIdx.x * blockDim.x + threadIdx.x) << 2;
    if (e4 + 4 <= E) {
        int4 s = *(const int4*)&src[e4];
        int4 d = *(const int4*)&dst[e4];
        csr_src[atomicAdd(&cursor[d.x], 1)] = s.x;
        csr_src[atomicAdd(&cursor[d.y], 1)] = s.y;
        csr_src[atomicAdd(&cursor[d.z], 1)] = s.z;
        csr_src[atomicAdd(&cursor[d.w], 1)] = s.w;
        atomicAdd(&alphaT[(size_t)s.x * N_GRAPHS + batch[d.x]], dinv[d.x]);
        atomicAdd(&alphaT[(size_t)s.y * N_GRAPHS + batch[d.y]], dinv[d.y]);
        atomicAdd(&alphaT[(size_t)s.z * N_GRAPHS + batch[d.z]], dinv[d.z]);
        atomicAdd(&alphaT[(size_t)s.w * N_GRAPHS + batch[d.w]], dinv[d.w]);
    } else {
        for (int e = e4; e < E; ++e) {
            int s = src[e], d = dst[e];
            csr_src[atomicAdd(&cursor[d], 1)] = s;
            atomicAdd(&alphaT[(size_t)s * N_GRAPHS + batch[d]], dinv[d]);
        }
    }
}

// ---------------------------------------------------------------- graph boundaries
__global__ void k_bounds(const int* __restrict__ batch, int* __restrict__ goff, int n) {
    int g = threadIdx.x;
    if (g > N_GRAPHS) return;
    int lo = 0, hi = n;
    while (lo < hi) {
        int m = (lo + hi) >> 1;
        if (batch[m] < g) lo = m + 1; else hi = m;
    }
    goff[g] = lo;
}

// ---------------------------------------------------------------- prep: xp = dinv*x (pad 8) ; alphaT self term
__global__ void k_prep(const float* __restrict__ x, const float* __restrict__ dinv,
                       const int* __restrict__ batch, float* __restrict__ xp,
                       float* __restrict__ alphaT, int n) {
    int t = blockIdx.x * blockDim.x + threadIdx.x;
    int i = t >> 3, j = t & 7;
    if (i >= n) return;
    xp[t] = (j < N_FEAT) ? dinv[i] * x[i * N_FEAT + j] : 0.f;
    if (j == 0) alphaT[(size_t)i * N_GRAPHS + batch[i]] += dinv[i];  // after k_fill, unique per i
}

// ---------------------------------------------------------------- layer-1 aggregation on 7-dim (L2-resident)
__global__ __launch_bounds__(256) void k_agg7(const float* __restrict__ xp,
                                              float* __restrict__ ax,
                                              const int* __restrict__ start,
                                              const int* __restrict__ csr_src,
                                              const float* __restrict__ dinv, int nnodes) {
    int t = blockIdx.x * blockDim.x + threadIdx.x;
    int g = t >> 3, j = t & 7;
    if (g >= nnodes) return;
    float acc = xp[(size_t)g * 8 + j];
    int e0 = start[g], e1 = start[g + 1];
    int e = e0;
    for (; e + 4 <= e1; e += 4) {
        int s0 = csr_src[e + 0], s1 = csr_src[e + 1];
        int s2 = csr_src[e + 2], s3 = csr_src[e + 3];
        acc += xp[(size_t)s0 * 8 + j] + xp[(size_t)s1 * 8 + j]
             + xp[(size_t)s2 * 8 + j] + xp[(size_t)s3 * 8 + j];
    }
    for (; e < e1; ++e) acc += xp[(size_t)csr_src[e] * 8 + j];
    ax[(size_t)g * 8 + j] = dinv[g] * acc;
}

// ---------------------------------------------------------------- layer-1 transform: h1 = relu(ax @ W1 + b1)
__global__ __launch_bounds__(256) void k_gemm7(const float* __restrict__ AX,
                                               const float* __restrict__ W1,
                                               const float* __restrict__ b1,
                                               float* __restrict__ h1, int n) {
    __shared__ float w[N_FEAT * HIDDEN];
    __shared__ float bs[HIDDEN];
    int tid = threadIdx.x;
    for (int i = tid; i < N_FEAT * HIDDEN; i += 256) w[i] = W1[i];
    if (tid < HIDDEN) bs[tid] = b1[tid];
    __syncthreads();
    int row = blockIdx.x * 2 + (tid >> 7);
    int col = tid & 127;
    if (row >= n) return;
    float acc = bs[col];
#pragma unroll
    for (int k = 0; k < N_FEAT; ++k)
        acc += AX[(size_t)row * 8 + k] * w[k * HIDDEN + col];
    h1[(size_t)row * HIDDEN + col] = fmaxf(acc, 0.f);
}

// ---------------------------------------------------------------- dense fp32 GEMM with dinv pre-scale: Ts = dinv*(A@W)
__global__ __launch_bounds__(256) void k_gemm128(const float* __restrict__ A,
                                                 const float* __restrict__ W,
                                                 const float* __restrict__ dinv,
                                                 float* __restrict__ Ts, int nrows) {
    __shared__ float as[16][68];
    __shared__ float ws[16][132];
    int row0 = blockIdx.x * 64;
    int tid = threadIdx.x;
    int tr = tid >> 4;
    int tc = tid & 15;
    float acc[4][8] = {};
    for (int k0 = 0; k0 < 128; k0 += 16) {
        {
            int r = tid >> 2;
            int ko = (tid & 3) << 2;
            float4 av = make_float4(0.f, 0.f, 0.f, 0.f);
            if (row0 + r < nrows)
                av = *(const float4*)&A[(size_t)(row0 + r) * 128 + k0 + ko];
            as[ko + 0][r] = av.x; as[ko + 1][r] = av.y;
            as[ko + 2][r] = av.z; as[ko + 3][r] = av.w;
        }
        {
            int wk = tid >> 4;
            int wc = (tid & 15) << 2;
            const float* wp = &W[(size_t)(k0 + wk) * 128 + wc];
            *(float4*)&ws[wk][wc]      = *(const float4*)(wp);
            *(float4*)&ws[wk][wc + 64] = *(const float4*)(wp + 64);
        }
        __syncthreads();
#pragma unroll
        for (int kk = 0; kk < 16; ++kk) {
            float a[4], b[8];
            *(float4*)&a[0] = *(const float4*)&as[kk][tr * 4];
            *(float4*)&b[0] = *(const float4*)&ws[kk][tc * 4];
            *(float4*)&b[4] = *(const float4*)&ws[kk][64 + tc * 4];
#pragma unroll
            for (int i = 0; i < 4; ++i)
#pragma unroll
                for (int j = 0; j < 8; ++j)
                    acc[i][j] += a[i] * b[j];
        }
        __syncthreads();
    }
#pragma unroll
    for (int i = 0; i < 4; ++i) {
        int rr = row0 + tr * 4 + i;
        if (rr < nrows) {
            float sc = dinv[rr];
            float* dstp = &Ts[(size_t)rr * 128];
            *(float4*)(dstp + tc * 4)      = make_float4(sc * acc[i][0], sc * acc[i][1], sc * acc[i][2], sc * acc[i][3]);
            *(float4*)(dstp + 64 + tc * 4) = make_float4(sc * acc[i][4], sc * acc[i][5], sc * acc[i][6], sc * acc[i][7]);
        }
    }
}

// ---------------------------------------------------------------- aggregation on pre-scaled Ts (layer 2 only):
__global__ __launch_bounds__(256) void k_agg(const float* __restrict__ Ts, float* __restrict__ H,
                                             const int* __restrict__ start,
                                             const int* __restrict__ csr_src,
                                             const float* __restrict__ dinv,
                                             const float* __restrict__ bias,
                                             int relu, int nnodes) {
    int g = (blockIdx.x * blockDim.x + threadIdx.x) >> 5;
    int lane = threadIdx.x & 31;
    if (g >= nnodes) return;
    const size_t loff = (size_t)lane * 4;
    float4 v = *(const float4*)&Ts[(size_t)g * 128 + loff];
    float ax = v.x, ay = v.y, az = v.z, aw = v.w;
    int e0 = start[g], e1 = start[g + 1];
    int e = e0;
    for (; e + 8 <= e1; e += 8) {
        int s[8];
        float4 u[8];
#pragma unroll
        for (int j = 0; j < 8; ++j) s[j] = csr_src[e + j];
#pragma unroll
        for (int j = 0; j < 8; ++j) u[j] = *(const float4*)&Ts[(size_t)s[j] * 128 + loff];
#pragma unroll
        for (int j = 0; j < 8; ++j) {
            ax += u[j].x; ay += u[j].y; az += u[j].z; aw += u[j].w;
        }
    }
    if (e + 4 <= e1) {
        int s[4];
        float4 u[4];
#pragma unroll
        for (int j = 0; j < 4; ++j) s[j] = csr_src[e + j];
#pragma unroll
        for (int j = 0; j < 4; ++j) u[j] = *(const float4*)&Ts[(size_t)s[j] * 128 + loff];
#pragma unroll
        for (int j = 0; j < 4; ++j) {
            ax += u[j].x; ay += u[j].y; az += u[j].z; aw += u[j].w;
        }
        e += 4;
    }
    for (; e < e1; ++e) {
        float4 u = *(const float4*)&Ts[(size_t)csr_src[e] * 128 + loff];
        ax += u.x; ay += u.y; az += u.z; aw += u.w;
    }
    float di = dinv[g];
    float4 b = *(const float4*)&bias[loff];
    ax = di * ax + b.x; ay = di * ay + b.y;
    az = di * az + b.z; aw = di * aw + b.w;
    if (relu) {
        ax = fmaxf(ax, 0.f); ay = fmaxf(ay, 0.f);
        az = fmaxf(az, 0.f); aw = fmaxf(aw, 0.f);
    }
    *(float4*)&H[(size_t)g * 128 + loff] = make_float4(ax, ay, az, aw);
}

// ---------------------------------------------------------------- q stage v3: split-K, per-block private partial (NO atomics)
// qpart[b][g][d] = sum_{s in chunk b} alphaT[s][g] * dinv[s] * H2[s][d]
__global__ __launch_bounds__(256) void k_qstage(const float* __restrict__ H,
                                                const float* __restrict__ alphaT,
                                                const float* __restrict__ dinv,
                                                float* __restrict__ qpart, int n) {
    int gg = threadIdx.x >> 5;     // graph octet 0..7
    int lane = threadIdx.x & 31;   // dims lane*4..+3
    int per = (n + gridDim.x - 1) / gridDim.x;
    int n0 = blockIdx.x * per;
    int n1 = min(n, n0 + per);
    float4 acc[8];
#pragma unroll
    for (int k = 0; k < 8; ++k) acc[k] = make_float4(0.f, 0.f, 0.f, 0.f);
    int s = n0;
    for (; s + 2 <= n1; s += 2) {
        float ds0 = dinv[s], ds1 = dinv[s + 1];
        float4 h0 = *(const float4*)&H[(size_t)s * 128 + lane * 4];
        float4 h1 = *(const float4*)&H[(size_t)(s + 1) * 128 + lane * 4];
        float4 a0lo = *(const float4*)&alphaT[(size_t)s * N_GRAPHS + gg * 8];
        float4 a0hi = *(const float4*)&alphaT[(size_t)s * N_GRAPHS + gg * 8 + 4];
        float4 a1lo = *(const float4*)&alphaT[(size_t)(s + 1) * N_GRAPHS + gg * 8];
        float4 a1hi = *(const float4*)&alphaT[(size_t)(s + 1) * N_GRAPHS + gg * 8 + 4];
        h0.x *= ds0; h0.y *= ds0; h0.z *= ds0; h0.w *= ds0;
        h1.x *= ds1; h1.y *= ds1; h1.z *= ds1; h1.w *= ds1;
        const float a0[8] = {a0lo.x, a0lo.y, a0lo.z, a0lo.w, a0hi.x, a0hi.y, a0hi.z, a0hi.w};
        const float a1[8] = {a1lo.x, a1lo.y, a1lo.z, a1lo.w, a1hi.x, a1hi.y, a1hi.z, a1hi.w};
#pragma unroll
        for (int k = 0; k < 8; ++k) {
            acc[k].x += a0[k] * h0.x + a1[k] * h1.x;
            acc[k].y += a0[k] * h0.y + a1[k] * h1.y;
            acc[k].z += a0[k] * h0.z + a1[k] * h1.z;
            acc[k].w += a0[k] * h0.w + a1[k] * h1.w;
        }
    }
    for (; s < n1; ++s) {
        float ds = dinv[s];
        float4 h = *(const float4*)&H[(size_t)s * 128 + lane * 4];
        h.x *= ds; h.y *= ds; h.z *= ds; h.w *= ds;
        float4 alo = *(const float4*)&alphaT[(size_t)s * N_GRAPHS + gg * 8];
        float4 ahi = *(const float4*)&alphaT[(size_t)s * N_GRAPHS + gg * 8 + 4];
        const float a[8] = {alo.x, alo.y, alo.z, alo.w, ahi.x, ahi.y, ahi.z, ahi.w};
#pragma unroll
        for (int k = 0; k < 8; ++k) {
            acc[k].x += a[k] * h.x; acc[k].y += a[k] * h.y;
            acc[k].z += a[k] * h.z; acc[k].w += a[k] * h.w;
        }
    }
    // store private partial (empty blocks store zeros: qpart aliases dead Ts memory, must be overwritten)
    float* dstp = &qpart[(size_t)blockIdx.x * (N_GRAPHS * HIDDEN)];
#pragma unroll
    for (int k = 0; k < 8; ++k)
        *(float4*)&dstp[(size_t)(gg * 8 + k) * HIDDEN + lane * 4] = acc[k];
}

// ---------------------------------------------------------------- q reduce over QBLOCKS partials
__global__ void k_qreduce(const float* __restrict__ qpart, float* __restrict__ q, int nblocks) {
    int t = blockIdx.x * blockDim.x + threadIdx.x;
    if (t >= N_GRAPHS * HIDDEN) return;
    float acc0 = 0.f, acc1 = 0.f, acc2 = 0.f, acc3 = 0.f;
    int b = 0;
    for (; b + 4 <= nblocks; b += 4) {
        acc0 += qpart[(size_t)(b + 0) * (N_GRAPHS * HIDDEN) + t];
        acc1 += qpart[(size_t)(b + 1) * (N_GRAPHS * HIDDEN) + t];
        acc2 += qpart[(size_t)(b + 2) * (N_GRAPHS * HIDDEN) + t];
        acc3 += qpart[(size_t)(b + 3) * (N_GRAPHS * HIDDEN) + t];
    }
    for (; b < nblocks; ++b) acc0 += qpart[(size_t)b * (N_GRAPHS * HIDDEN) + t];
    q[t] = (acc0 + acc1) + (acc2 + acc3);
}

// ---------------------------------------------------------------- Wc = W3 @ Wl [128,2]; bc = b3 @ Wl + bl
__global__ void k_wc(const float* __restrict__ W3, const float* __restrict__ Wl,
                     const float* __restrict__ b3, const float* __restrict__ bl,
                     float* __restrict__ Wc, float* __restrict__ bc) {
    int t = threadIdx.x;               // 256 threads: k=t>>1 (0..127), c=t&1
    int k = t >> 1, c = t & 1;
    float acc = 0.f;
#pragma unroll 8
    for (int j = 0; j < HIDDEN; ++j) acc += W3[k * HIDDEN + j] * Wl[j * N_CLASSES + c];
    Wc[k * N_CLASSES + c] = acc;
    if (k == 0) {
        float b = bl[c];
        for (int j = 0; j < HIDDEN; ++j) b += b3[j] * Wl[j * N_CLASSES + c];
        bc[c] = b;
    }
}

// ---------------------------------------------------------------- final: out[g][c] = (q[g]@Wc)[c]/cnt + bc[c]
__global__ void k_final2(const float* __restrict__ q, const float* __restrict__ Wc,
                         const float* __restrict__ bc, const int* __restrict__ goff,
                         float* __restrict__ out) {
    int t = threadIdx.x;               // 128 threads
    int g = t >> 1, c = t & 1;
    float inv = 1.0f / (float)max(goff[g + 1] - goff[g], 1);
    float acc = 0.f;
#pragma unroll 8
    for (int k = 0; k < HIDDEN; ++k) acc += q[g * HIDDEN + k] * Wc[k * N_CLASSES + c];
    out[g * N_CLASSES + c] = acc * inv + bc[c];
}

// ================================================================ launch
extern "C" void kernel_launch(void* const* d_in, const int* in_sizes, int n_in,
                              void* d_out, int out_size, void* d_ws, size_t ws_size,
                              hipStream_t stream) {
    const float* x    = (const float*)d_in[0];
    const int*   ei   = (const int*)d_in[1];
    const int*   batch= (const int*)d_in[2];
    const float* W1   = (const float*)d_in[3];
    const float* b1   = (const float*)d_in[4];
    const float* W2   = (const float*)d_in[5];
    const float* b2   = (const float*)d_in[6];
    const float* W3   = (const float*)d_in[7];
    const float* b3   = (const float*)d_in[8];
    const float* Wl   = (const float*)d_in[9];
    const float* bl   = (const float*)d_in[10];
    float* out = (float*)d_out;

    const int N = in_sizes[0] / N_FEAT;        // 40000
    const int E = in_sizes[1] / 2;             // 640000
    const int* e_src = ei;
    const int* e_dst = ei + E;
    const int B = (N + SCAN_TILE - 1) / SCAN_TILE;

    // workspace carve-out (256B aligned)
    char* ws = (char*)d_ws;
    auto carve = [&](size_t bytes) -> char* {
        char* p = ws;
        ws += (bytes + 255) & ~(size_t)255;
        return p;
    };
    float* T        = (float*)carve((size_t)N * HIDDEN * 4);   // Ts; later reused as qpart (dead after k_agg)
    float* H        = (float*)carve((size_t)N * HIDDEN * 4);   // h1 then h2
    float* xp       = (float*)carve((size_t)N * 8 * 4);
    float* ax       = (float*)carve((size_t)N * 8 * 4);
    int*   deg      = (int*)  carve((size_t)N * 4);
    int*   start    = (int*)  carve((size_t)(N + 1) * 4);
    int*   cursor   = (int*)  carve((size_t)N * 4);
    float* dinv     = (float*)carve((size_t)N * 4);
    int*   csr_src  = (int*)  carve((size_t)E * 4);
    float* alphaT   = (float*)carve((size_t)N * N_GRAPHS * 4); // 10.2 MB
    float* q        = (float*)carve((size_t)N_GRAPHS * HIDDEN * 4);
    float* Wc       = (float*)carve((size_t)HIDDEN * N_CLASSES * 4);
    float* bc       = (float*)carve((size_t)N_CLASSES * 4);
    int*   goff     = (int*)  carve((size_t)(N_GRAPHS + 1) * 4);
    int*   bsum     = (int*)  carve((size_t)B * 4);
    int*   boff     = (int*)  carve((size_t)B * 4);
    if ((size_t)(ws - (char*)d_ws) > ws_size) return;

    float* qpart = T;   // alias: Ts is dead after layer-2 agg; QBLOCKS*64*128*4 = 16.8MB <= 20.5MB

    // --- CSR + alphaT build + graph bounds ---
    k_zero  <<<(N * N_GRAPHS + 255) / 256, 256, 0, stream>>>(deg, alphaT, N);
    k_count <<<(E / 4 + 255) / 256, 256, 0, stream>>>(e_dst, deg, E);
    k_scan_a<<<B, 1024, 0, stream>>>(deg, bsum, N);
    k_scan_b<<<1, 1024, 0, stream>>>(bsum, boff, start, B, N);
    k_scan_c<<<B, 1024, 0, stream>>>(deg, boff, start, cursor, dinv, N);
    k_fill  <<<(E / 4 + 255) / 256, 256, 0, stream>>>(e_src, e_dst, batch, dinv, cursor, csr_src, alphaT, E);
    k_bounds<<<1, 128, 0, stream>>>(batch, goff, N);

    const int aggBlocks  = (N * 32 + 255) / 256;
    const int gemmBlocks = (N + 63) / 64;

    // --- layer 1: aggregate 7-dim, then transform ---
    k_prep <<<(N * 8 + 255) / 256, 256, 0, stream>>>(x, dinv, batch, xp, alphaT, N);
    k_agg7 <<<(N * 8 + 255) / 256, 256, 0, stream>>>(xp, ax, start, csr_src, dinv, N);
    k_gemm7<<<(N + 1) / 2, 256, 0, stream>>>(ax, W1, b1, H, N);   // H = h1
    // --- layer 2 ---
    k_gemm128<<<gemmBlocks, 256, 0, stream>>>(H, W2, dinv, T, N); // T = dinv*(h1@W2)
    k_agg    <<<aggBlocks, 256, 0, stream>>>(T, H, start, csr_src, dinv, b2, 1, N);  // H = h2 (T now dead)
    // --- layer 3 + pool + classifier, collapsed by linearity ---
    k_qstage <<<QBLOCKS, 256, 0, stream>>>(H, alphaT, dinv, qpart, N);
    k_qreduce<<<(N_GRAPHS * HIDDEN + 255) / 256, 256, 0, stream>>>(qpart, q, QBLOCKS);
    k_wc     <<<1, 256, 0, stream>>>(W3, Wl, b3, bl, Wc, bc);
    k_final2 <<<1, 128, 0, stream>>>(q, Wc, bc, goff, out);
}

// Round 12
// 278.676 us; speedup vs baseline: 1.5376x; 1.0006x over previous
//
#include <hip/hip_runtime.h>
#include <hip/hip_bf16.h>

#define N_FEAT 7
#define HIDDEN 128
#define N_CLASSES 2
#define N_GRAPHS 64
#define SCAN_TILE 1024
#define QBLOCKS 512   // qpart (64*128 floats per block) aliases dead Ts buffer: 512*32KB = 16.8MB < 20.5MB

// ---------------------------------------------------------------- zero init: deg[N] + alphaT[N*64]
__global__ void k_zero(int* __restrict__ deg, float* __restrict__ alphaT, int n) {
    int i = blockIdx.x * blockDim.x + threadIdx.x;
    if (i < n) deg[i] = 0;
    if (i < n * N_GRAPHS) alphaT[i] = 0.f;
}

// ---------------------------------------------------------------- degree count (4 edges/thread)
__global__ void k_count(const int* __restrict__ dst, int* __restrict__ deg, int E) {
    int e4 = (blockIdx.x * blockDim.x + threadIdx.x) << 2;
    if (e4 + 4 <= E) {
        int4 d = *(const int4*)&dst[e4];
        atomicAdd(&deg[d.x], 1);
        atomicAdd(&deg[d.y], 1);
        atomicAdd(&deg[d.z], 1);
        atomicAdd(&deg[d.w], 1);
    } else {
        for (int e = e4; e < E; ++e) atomicAdd(&deg[dst[e]], 1);
    }
}

// ---------------------------------------------------------------- scan phase A
__global__ __launch_bounds__(1024) void k_scan_a(const int* __restrict__ deg,
                                                 int* __restrict__ bsum, int n) {
    __shared__ int s[SCAN_TILE];
    int tid = threadIdx.x;
    int i = blockIdx.x * SCAN_TILE + tid;
    s[tid] = (i < n) ? deg[i] : 0;
    __syncthreads();
#pragma unroll
    for (int off = 512; off > 0; off >>= 1) {
        if (tid < off) s[tid] += s[tid + off];
        __syncthreads();
    }
    if (tid == 0) bsum[blockIdx.x] = s[0];
}

// ---------------------------------------------------------------- scan phase B (1 block)
__global__ __launch_bounds__(1024) void k_scan_b(const int* __restrict__ bsum,
                                                 int* __restrict__ boff,
                                                 int* __restrict__ start, int B, int n) {
    __shared__ int s[SCAN_TILE];
    int tid = threadIdx.x;
    int v = (tid < B) ? bsum[tid] : 0;
    s[tid] = v;
    __syncthreads();
    for (int off = 1; off < SCAN_TILE; off <<= 1) {
        int t = (tid >= off) ? s[tid - off] : 0;
        __syncthreads();
        s[tid] += t;
        __syncthreads();
    }
    if (tid < B) boff[tid] = s[tid] - v;
    if (tid == B - 1) start[n] = s[tid];
}

// ---------------------------------------------------------------- scan phase C
__global__ __launch_bounds__(1024) void k_scan_c(const int* __restrict__ deg,
                                                 const int* __restrict__ boff,
                                                 int* __restrict__ start,
                                                 int* __restrict__ cursor,
                                                 float* __restrict__ dinv, int n) {
    __shared__ int s[SCAN_TILE];
    int tid = threadIdx.x;
    int i = blockIdx.x * SCAN_TILE + tid;
    int v = (i < n) ? deg[i] : 0;
    s[tid] = v;
    __syncthreads();
    for (int off = 1; off < SCAN_TILE; off <<= 1) {
        int t = (tid >= off) ? s[tid - off] : 0;
        __syncthreads();
        s[tid] += t;
        __syncthreads();
    }
    if (i < n) {
        int ex = boff[blockIdx.x] + s[tid] - v;
        start[i] = ex;
        cursor[i] = ex;
        dinv[i] = rsqrtf((float)(v + 1));
    }
}

// ---------------------------------------------------------------- CSR fill + alphaT edge scatter:
// csr_src[pos]=src ; alphaT[src][batch[dst]] += dinv[dst]
__global__ void k_fill(const int* __restrict__ src, const int* __restrict__ dst,
                       const int* __restrict__ batch, const float* __restrict__ dinv,
                       int* __restrict__ cursor, int* __restrict__ csr_src,
                       float* __restrict__ alphaT, int E) {
    int e4 = (blockIdx.x * blockDim.x + threadIdx.x) << 2;
    if (e4 + 4 <= E) {
        int4 s = *(const int4*)&src[e4];
        int4 d = *(const int4*)&dst[e4];
        csr_src[atomicAdd(&cursor[d.x], 1)] = s.x;
        csr_src[atomicAdd(&cursor[d.y], 1)] = s.y;
        csr_src[atomicAdd(&cursor[d.z], 1)] = s.z;
        csr_src[atomicAdd(&cursor[d.w], 1)] = s.w;
        atomicAdd(&alphaT[(size_t)s.x * N_GRAPHS + batch[d.x]], dinv[d.x]);
        atomicAdd(&alphaT[(size_t)s.y * N_GRAPHS + batch[d.y]], dinv[d.y]);
        atomicAdd(&alphaT[(size_t)s.z * N_GRAPHS + batch[d.z]], dinv[d.z]);
        atomicAdd(&alphaT[(size_t)s.w * N_GRAPHS + batch[d.w]], dinv[d.w]);
    } else {
        for (int e = e4; e < E; ++e) {
            int s = src[e], d = dst[e];
            csr_src[atomicAdd(&cursor[d], 1)] = s;
            atomicAdd(&alphaT[(size_t)s * N_GRAPHS + batch[d]], dinv[d]);
        }
    }
}

// ---------------------------------------------------------------- graph boundaries
__global__ void k_bounds(const int* __restrict__ batch, int* __restrict__ goff, int n) {
    int g = threadIdx.x;
    if (g > N_GRAPHS) return;
    int lo = 0, hi = n;
    while (lo < hi) {
        int m = (lo + hi) >> 1;
        if (batch[m] < g) lo = m + 1; else hi = m;
    }
    goff[g] = lo;
}

// ---------------------------------------------------------------- prep: xp = dinv*x (pad 8) ; alphaT self term
__global__ void k_prep(const float* __restrict__ x, const float* __restrict__ dinv,
                       const int* __restrict__ batch, float* __restrict__ xp,
                       float* __restrict__ alphaT, int n) {
    int t = blockIdx.x * blockDim.x + threadIdx.x;
    int i = t >> 3, j = t & 7;
    if (i >= n) return;
    xp[t] = (j < N_FEAT) ? dinv[i] * x[i * N_FEAT + j] : 0.f;
    if (j == 0) alphaT[(size_t)i * N_GRAPHS + batch[i]] += dinv[i];  // after k_fill, unique per i
}

// ---------------------------------------------------------------- layer-1 aggregation on 7-dim (L2-resident)
__global__ __launch_bounds__(256) void k_agg7(const float* __restrict__ xp,
                                              float* __restrict__ ax,
                                              const int* __restrict__ start,
                                              const int* __restrict__ csr_src,
                                              const float* __restrict__ dinv, int nnodes) {
    int t = blockIdx.x * blockDim.x + threadIdx.x;
    int g = t >> 3, j = t & 7;
    if (g >= nnodes) return;
    float acc = xp[(size_t)g * 8 + j];
    int e0 = start[g], e1 = start[g + 1];
    int e = e0;
    for (; e + 4 <= e1; e += 4) {
        int s0 = csr_src[e + 0], s1 = csr_src[e + 1];
        int s2 = csr_src[e + 2], s3 = csr_src[e + 3];
        acc += xp[(size_t)s0 * 8 + j] + xp[(size_t)s1 * 8 + j]
             + xp[(size_t)s2 * 8 + j] + xp[(size_t)s3 * 8 + j];
    }
    for (; e < e1; ++e) acc += xp[(size_t)csr_src[e] * 8 + j];
    ax[(size_t)g * 8 + j] = dinv[g] * acc;
}

// ---------------------------------------------------------------- layer-1 transform: h1 = relu(ax @ W1 + b1)
__global__ __launch_bounds__(256) void k_gemm7(const float* __restrict__ AX,
                                               const float* __restrict__ W1,
                                               const float* __restrict__ b1,
                                               float* __restrict__ h1, int n) {
    __shared__ float w[N_FEAT * HIDDEN];
    __shared__ float bs[HIDDEN];
    int tid = threadIdx.x;
    for (int i = tid; i < N_FEAT * HIDDEN; i += 256) w[i] = W1[i];
    if (tid < HIDDEN) bs[tid] = b1[tid];
    __syncthreads();
    int row = blockIdx.x * 2 + (tid >> 7);
    int col = tid & 127;
    if (row >= n) return;
    float acc = bs[col];
#pragma unroll
    for (int k = 0; k < N_FEAT; ++k)
        acc += AX[(size_t)row * 8 + k] * w[k * HIDDEN + col];
    h1[(size_t)row * HIDDEN + col] = fmaxf(acc, 0.f);
}

// ---------------------------------------------------------------- dense fp32 GEMM with dinv pre-scale: Ts = dinv*(A@W)
__global__ __launch_bounds__(256) void k_gemm128(const float* __restrict__ A,
                                                 const float* __restrict__ W,
                                                 const float* __restrict__ dinv,
                                                 float* __restrict__ Ts, int nrows) {
    __shared__ float as[16][68];
    __shared__ float ws[16][132];
    int row0 = blockIdx.x * 64;
    int tid = threadIdx.x;
    int tr = tid >> 4;
    int tc = tid & 15;
    float acc[4][8] = {};
    for (int k0 = 0; k0 < 128; k0 += 16) {
        {
            int r = tid >> 2;
            int ko = (tid & 3) << 2;
            float4 av = make_float4(0.f, 0.f, 0.f, 0.f);
            if (row0 + r < nrows)
                av = *(const float4*)&A[(size_t)(row0 + r) * 128 + k0 + ko];
            as[ko + 0][r] = av.x; as[ko + 1][r] = av.y;
            as[ko + 2][r] = av.z; as[ko + 3][r] = av.w;
        }
        {
            int wk = tid >> 4;
            int wc = (tid & 15) << 2;
            const float* wp = &W[(size_t)(k0 + wk) * 128 + wc];
            *(float4*)&ws[wk][wc]      = *(const float4*)(wp);
            *(float4*)&ws[wk][wc + 64] = *(const float4*)(wp + 64);
        }
        __syncthreads();
#pragma unroll
        for (int kk = 0; kk < 16; ++kk) {
            float a[4], b[8];
            *(float4*)&a[0] = *(const float4*)&as[kk][tr * 4];
            *(float4*)&b[0] = *(const float4*)&ws[kk][tc * 4];
            *(float4*)&b[4] = *(const float4*)&ws[kk][64 + tc * 4];
#pragma unroll
            for (int i = 0; i < 4; ++i)
#pragma unroll
                for (int j = 0; j < 8; ++j)
                    acc[i][j] += a[i] * b[j];
        }
        __syncthreads();
    }
#pragma unroll
    for (int i = 0; i < 4; ++i) {
        int rr = row0 + tr * 4 + i;
        if (rr < nrows) {
            float sc = dinv[rr];
            float* dstp = &Ts[(size_t)rr * 128];
            *(float4*)(dstp + tc * 4)      = make_float4(sc * acc[i][0], sc * acc[i][1], sc * acc[i][2], sc * acc[i][3]);
            *(float4*)(dstp + 64 + tc * 4) = make_float4(sc * acc[i][4], sc * acc[i][5], sc * acc[i][6], sc * acc[i][7]);
        }
    }
}

// ---------------------------------------------------------------- aggregation on pre-scaled Ts (layer 2 only):
__global__ __launch_bounds__(256) void k_agg(const float* __restrict__ Ts, float* __restrict__ H,
                                             const int* __restrict__ start,
                                             const int* __restrict__ csr_src,
                                             const float* __restrict__ dinv,
                                             const float* __restrict__ bias,
                                             int relu, int nnodes) {
    int g = (blockIdx.x * blockDim.x + threadIdx.x) >> 5;
    int lane = threadIdx.x & 31;
    if (g >= nnodes) return;
    const size_t loff = (size_t)lane * 4;
    float4 v = *(const float4*)&Ts[(size_t)g * 128 + loff];
    float ax = v.x, ay = v.y, az = v.z, aw = v.w;
    int e0 = start[g], e1 = start[g + 1];
    int e = e0;
    for (; e + 8 <= e1; e += 8) {
        int s[8];
        float4 u[8];
#pragma unroll
        for (int j = 0; j < 8; ++j) s[j] = csr_src[e + j];
#pragma unroll
        for (int j = 0; j < 8; ++j) u[j] = *(const float4*)&Ts[(size_t)s[j] * 128 + loff];
#pragma unroll
        for (int j = 0; j < 8; ++j) {
            ax += u[j].x; ay += u[j].y; az += u[j].z; aw += u[j].w;
        }
    }
    if (e + 4 <= e1) {
        int s[4];
        float4 u[4];
#pragma unroll
        for (int j = 0; j < 4; ++j) s[j] = csr_src[e + j];
#pragma unroll
        for (int j = 0; j < 4; ++j) u[j] = *(const float4*)&Ts[(size_t)s[j] * 128 + loff];
#pragma unroll
        for (int j = 0; j < 4; ++j) {
            ax += u[j].x; ay += u[j].y; az += u[j].z; aw += u[j].w;
        }
        e += 4;
    }
    for (; e < e1; ++e) {
        float4 u = *(const float4*)&Ts[(size_t)csr_src[e] * 128 + loff];
        ax += u.x; ay += u.y; az += u.z; aw += u.w;
    }
    float di = dinv[g];
    float4 b = *(const float4*)&bias[loff];
    ax = di * ax + b.x; ay = di * ay + b.y;
    az = di * az + b.z; aw = di * aw + b.w;
    if (relu) {
        ax = fmaxf(ax, 0.f); ay = fmaxf(ay, 0.f);
        az = fmaxf(az, 0.f); aw = fmaxf(aw, 0.f);
    }
    *(float4*)&H[(size_t)g * 128 + loff] = make_float4(ax, ay, az, aw);
}

// ---------------------------------------------------------------- q stage v3: split-K, per-block private partial (NO atomics)
// qpart[b][g][d] = sum_{s in chunk b} alphaT[s][g] * dinv[s] * H2[s][d]
__global__ __launch_bounds__(256) void k_qstage(const float* __restrict__ H,
                                                const float* __restrict__ alphaT,
                                                const float* __restrict__ dinv,
                                                float* __restrict__ qpart, int n) {
    int gg = threadIdx.x >> 5;     // graph octet 0..7
    int lane = threadIdx.x & 31;   // dims lane*4..+3
    int per = (n + gridDim.x - 1) / gridDim.x;
    int n0 = blockIdx.x * per;
    int n1 = min(n, n0 + per);
    float4 acc[8];
#pragma unroll
    for (int k = 0; k < 8; ++k) acc[k] = make_float4(0.f, 0.f, 0.f, 0.f);
    int s = n0;
    for (; s + 2 <= n1; s += 2) {
        float ds0 = dinv[s], ds1 = dinv[s + 1];
        float4 h0 = *(const float4*)&H[(size_t)s * 128 + lane * 4];
        float4 h1 = *(const float4*)&H[(size_t)(s + 1) * 128 + lane * 4];
        float4 a0lo = *(const float4*)&alphaT[(size_t)s * N_GRAPHS + gg * 8];
        float4 a0hi = *(const float4*)&alphaT[(size_t)s * N_GRAPHS + gg * 8 + 4];
        float4 a1lo = *(const float4*)&alphaT[(size_t)(s + 1) * N_GRAPHS + gg * 8];
        float4 a1hi = *(const float4*)&alphaT[(size_t)(s + 1) * N_GRAPHS + gg * 8 + 4];
        h0.x *= ds0; h0.y *= ds0; h0.z *= ds0; h0.w *= ds0;
        h1.x *= ds1; h1.y *= ds1; h1.z *= ds1; h1.w *= ds1;
        const float a0[8] = {a0lo.x, a0lo.y, a0lo.z, a0lo.w, a0hi.x, a0hi.y, a0hi.z, a0hi.w};
        const float a1[8] = {a1lo.x, a1lo.y, a1lo.z, a1lo.w, a1hi.x, a1hi.y, a1hi.z, a1hi.w};
#pragma unroll
        for (int k = 0; k < 8; ++k) {
            acc[k].x += a0[k] * h0.x + a1[k] * h1.x;
            acc[k].y += a0[k] * h0.y + a1[k] * h1.y;
            acc[k].z += a0[k] * h0.z + a1[k] * h1.z;
            acc[k].w += a0[k] * h0.w + a1[k] * h1.w;
        }
    }
    for (; s < n1; ++s) {
        float ds = dinv[s];
        float4 h = *(const float4*)&H[(size_t)s * 128 + lane * 4];
        h.x *= ds; h.y *= ds; h.z *= ds; h.w *= ds;
        float4 alo = *(const float4*)&alphaT[(size_t)s * N_GRAPHS + gg * 8];
        float4 ahi = *(const float4*)&alphaT[(size_t)s * N_GRAPHS + gg * 8 + 4];
        const float a[8] = {alo.x, alo.y, alo.z, alo.w, ahi.x, ahi.y, ahi.z, ahi.w};
#pragma unroll
        for (int k = 0; k < 8; ++k) {
            acc[k].x += a[k] * h.x; acc[k].y += a[k] * h.y;
            acc[k].z += a[k] * h.z; acc[k].w += a[k] * h.w;
        }
    }
    // store private partial (empty blocks store zeros: qpart aliases dead Ts memory, must be overwritten)
    float* dstp = &qpart[(size_t)blockIdx.x * (N_GRAPHS * HIDDEN)];
#pragma unroll
    for (int k = 0; k < 8; ++k)
        *(float4*)&dstp[(size_t)(gg * 8 + k) * HIDDEN + lane * 4] = acc[k];
}

// ---------------------------------------------------------------- q reduce over QBLOCKS partials
__global__ void k_qreduce(const float* __restrict__ qpart, float* __restrict__ q, int nblocks) {
    int t = blockIdx.x * blockDim.x + threadIdx.x;
    if (t >= N_GRAPHS * HIDDEN) return;
    float acc0 = 0.f, acc1 = 0.f, acc2 = 0.f, acc3 = 0.f;
    int b = 0;
    for (; b + 4 <= nblocks; b += 4) {
        acc0 += qpart[(size_t)(b + 0) * (N_GRAPHS * HIDDEN) + t];
        acc1 += qpart[(size_t)(b + 1) * (N_GRAPHS * HIDDEN) + t];
        acc2 += qpart[(size_t)(b + 2) * (N_GRAPHS * HIDDEN) + t];
        acc3 += qpart[(size_t)(b + 3) * (N_GRAPHS * HIDDEN) + t];
    }
    for (; b < nblocks; ++b) acc0 += qpart[(size_t)b * (N_GRAPHS * HIDDEN) + t];
    q[t] = (acc0 + acc1) + (acc2 + acc3);
}

// ---------------------------------------------------------------- Wc = W3 @ Wl [128,2]; bc = b3 @ Wl + bl
__global__ void k_wc(const float* __restrict__ W3, const float* __restrict__ Wl,
                     const float* __restrict__ b3, const float* __restrict__ bl,
                     float* __restrict__ Wc, float* __restrict__ bc) {
    int t = threadIdx.x;               // 256 threads: k=t>>1 (0..127), c=t&1
    int k = t >> 1, c = t & 1;
    float acc = 0.f;
#pragma unroll 8
    for (int j = 0; j < HIDDEN; ++j) acc += W3[k * HIDDEN + j] * Wl[j * N_CLASSES + c];
    Wc[k * N_CLASSES + c] = acc;
    if (k == 0) {
        float b = bl[c];
        for (int j = 0; j < HIDDEN; ++j) b += b3[j] * Wl[j * N_CLASSES + c];
        bc[c] = b;
    }
}

// ---------------------------------------------------------------- final: out[g][c] = (q[g]@Wc)[c]/cnt + bc[c]
__global__ void k_final2(const float* __restrict__ q, const float* __restrict__ Wc,
                         const float* __restrict__ bc, const int* __restrict__ goff,
                         float* __restrict__ out) {
    int t = threadIdx.x;               // 128 threads
    int g = t >> 1, c = t & 1;
    float inv = 1.0f / (float)max(goff[g + 1] - goff[g], 1);
    float acc = 0.f;
#pragma unroll 8
    for (int k = 0; k < HIDDEN; ++k) acc += q[g * HIDDEN + k] * Wc[k * N_CLASSES + c];
    out[g * N_CLASSES + c] = acc * inv + bc[c];
}

// ================================================================ launch
extern "C" void kernel_launch(void* const* d_in, const int* in_sizes, int n_in,
                              void* d_out, int out_size, void* d_ws, size_t ws_size,
                              hipStream_t stream) {
    const float* x    = (const float*)d_in[0];
    const int*   ei   = (const int*)d_in[1];
    const int*   batch= (const int*)d_in[2];
    const float* W1   = (const float*)d_in[3];
    const float* b1   = (const float*)d_in[4];
    const float* W2   = (const float*)d_in[5];
    const float* b2   = (const float*)d_in[6];
    const float* W3   = (const float*)d_in[7];
    const float* b3   = (const float*)d_in[8];
    const float* Wl   = (const float*)d_in[9];
    const float* bl   = (const float*)d_in[10];
    float* out = (float*)d_out;

    const int N = in_sizes[0] / N_FEAT;        // 40000
    const int E = in_sizes[1] / 2;             // 640000
    const int* e_src = ei;
    const int* e_dst = ei + E;
    const int B = (N + SCAN_TILE - 1) / SCAN_TILE;

    // workspace carve-out (256B aligned)
    char* ws = (char*)d_ws;
    auto carve = [&](size_t bytes) -> char* {
        char* p = ws;
        ws += (bytes + 255) & ~(size_t)255;
        return p;
    };
    float* T        = (float*)carve((size_t)N * HIDDEN * 4);   // Ts; later reused as qpart (dead after k_agg)
    float* H        = (float*)carve((size_t)N * HIDDEN * 4);   // h1 then h2
    float* xp       = (float*)carve((size_t)N * 8 * 4);
    float* ax       = (float*)carve((size_t)N * 8 * 4);
    int*   deg      = (int*)  carve((size_t)N * 4);
    int*   start    = (int*)  carve((size_t)(N + 1) * 4);
    int*   cursor   = (int*)  carve((size_t)N * 4);
    float* dinv     = (float*)carve((size_t)N * 4);
    int*   csr_src  = (int*)  carve((size_t)E * 4);
    float* alphaT   = (float*)carve((size_t)N * N_GRAPHS * 4); // 10.2 MB
    float* q        = (float*)carve((size_t)N_GRAPHS * HIDDEN * 4);
    float* Wc       = (float*)carve((size_t)HIDDEN * N_CLASSES * 4);
    float* bc       = (float*)carve((size_t)N_CLASSES * 4);
    int*   goff     = (int*)  carve((size_t)(N_GRAPHS + 1) * 4);
    int*   bsum     = (int*)  carve((size_t)B * 4);
    int*   boff     = (int*)  carve((size_t)B * 4);
    if ((size_t)(ws - (char*)d_ws) > ws_size) return;

    float* qpart = T;   // alias: Ts is dead after layer-2 agg; QBLOCKS*64*128*4 = 16.8MB <= 20.5MB

    // --- CSR + alphaT build + graph bounds ---
    k_zero  <<<(N * N_GRAPHS + 255) / 256, 256, 0, stream>>>(deg, alphaT, N);
    k_count <<<(E / 4 + 255) / 256, 256, 0, stream>>>(e_dst, deg, E);
    k_scan_a<<<B, 1024, 0, stream>>>(deg, bsum, N);
    k_scan_b<<<1, 1024, 0, stream>>>(bsum, boff, start, B, N);
    k_scan_c<<<B, 1024, 0, stream>>>(deg, boff, start, cursor, dinv, N);
    k_fill  <<<(E / 4 + 255) / 256, 256, 0, stream>>>(e_src, e_dst, batch, dinv, cursor, csr_src, alphaT, E);
    k_bounds<<<1, 128, 0, stream>>>(batch, goff, N);

    const int aggBlocks  = (N * 32 + 255) / 256;
    const int gemmBlocks = (N + 63) / 64;

    // --- layer 1: aggregate 7-dim, then transform ---
    k_prep <<<(N * 8 + 255) / 256, 256, 0, stream>>>(x, dinv, batch, xp, alphaT, N);
    k_agg7 <<<(N * 8 + 255) / 256, 256, 0, stream>>>(xp, ax, start, csr_src, dinv, N);
    k_gemm7<<<(N + 1) / 2, 256, 0, stream>>>(ax, W1, b1, H, N);   // H = h1
    // --- layer 2 ---
    k_gemm128<<<gemmBlocks, 256, 0, stream>>>(H, W2, dinv, T, N); // T = dinv*(h1@W2)
    k_agg    <<<aggBlocks, 256, 0, stream>>>(T, H, start, csr_src, dinv, b2, 1, N);  // H = h2 (T now dead)
    // --- layer 3 + pool + classifier, collapsed by linearity ---
    k_qstage <<<QBLOCKS, 256, 0, stream>>>(H, alphaT, dinv, qpart, N);
    k_qreduce<<<(N_GRAPHS * HIDDEN + 255) / 256, 256, 0, stream>>>(qpart, q, QBLOCKS);
    k_wc     <<<1, 256, 0, stream>>>(W3, Wl, b3, bl, Wc, bc);
    k_final2 <<<1, 128, 0, stream>>>(q, Wc, bc, goff, out);
}

// Round 13
// 220.758 us; speedup vs baseline: 1.9410x; 1.2624x over previous
//
#include <hip/hip_runtime.h>
#include <hip/hip_bf16.h>
#include <hip/hip_fp16.h>

#define N_FEAT 7
#define HIDDEN 128
#define N_CLASSES 2
#define N_GRAPHS 64
#define SCAN_TILE 1024

// ---------------------------------------------------------------- fp16 helpers
__device__ __forceinline__ float4 ldh4(const __half* p) {
    uint2 v = *(const uint2*)p;                    // 4 halves, 8B
    __half2 a = *reinterpret_cast<__half2*>(&v.x);
    __half2 b = *reinterpret_cast<__half2*>(&v.y);
    float2 fa = __half22float2(a), fb = __half22float2(b);
    return make_float4(fa.x, fa.y, fb.x, fb.y);
}
__device__ __forceinline__ void sth4(__half* p, float a, float b, float c, float d) {
    __half2 lo = __floats2half2_rn(a, b);
    __half2 hi = __floats2half2_rn(c, d);
    uint2 v;
    v.x = *reinterpret_cast<unsigned int*>(&lo);
    v.y = *reinterpret_cast<unsigned int*>(&hi);
    *(uint2*)p = v;
}

// ---------------------------------------------------------------- zero init
__global__ void k_zero(int* __restrict__ deg, float* __restrict__ gsum, int n) {
    int i = blockIdx.x * blockDim.x + threadIdx.x;
    if (i < n) deg[i] = 0;
    if (i < N_GRAPHS * HIDDEN) gsum[i] = 0.f;
}

// ---------------------------------------------------------------- degree count (4 edges/thread)
__global__ void k_count(const int* __restrict__ dst, int* __restrict__ deg, int E) {
    int e4 = (blockIdx.x * blockDim.x + threadIdx.x) << 2;
    if (e4 + 4 <= E) {
        int4 d = *(const int4*)&dst[e4];
        atomicAdd(&deg[d.x], 1);
        atomicAdd(&deg[d.y], 1);
        atomicAdd(&deg[d.z], 1);
        atomicAdd(&deg[d.w], 1);
    } else {
        for (int e = e4; e < E; ++e) atomicAdd(&deg[dst[e]], 1);
    }
}

// ---------------------------------------------------------------- scan phase A
__global__ __launch_bounds__(1024) void k_scan_a(const int* __restrict__ deg,
                                                 int* __restrict__ bsum, int n) {
    __shared__ int s[SCAN_TILE];
    int tid = threadIdx.x;
    int i = blockIdx.x * SCAN_TILE + tid;
    s[tid] = (i < n) ? deg[i] : 0;
    __syncthreads();
#pragma unroll
    for (int off = 512; off > 0; off >>= 1) {
        if (tid < off) s[tid] += s[tid + off];
        __syncthreads();
    }
    if (tid == 0) bsum[blockIdx.x] = s[0];
}

// ---------------------------------------------------------------- scan phase B (1 block)
__global__ __launch_bounds__(1024) void k_scan_b(const int* __restrict__ bsum,
                                                 int* __restrict__ boff,
                                                 int* __restrict__ start, int B, int n) {
    __shared__ int s[SCAN_TILE];
    int tid = threadIdx.x;
    int v = (tid < B) ? bsum[tid] : 0;
    s[tid] = v;
    __syncthreads();
    for (int off = 1; off < SCAN_TILE; off <<= 1) {
        int t = (tid >= off) ? s[tid - off] : 0;
        __syncthreads();
        s[tid] += t;
        __syncthreads();
    }
    if (tid < B) boff[tid] = s[tid] - v;
    if (tid == B - 1) start[n] = s[tid];
}

// ---------------------------------------------------------------- scan phase C
__global__ __launch_bounds__(1024) void k_scan_c(const int* __restrict__ deg,
                                                 const int* __restrict__ boff,
                                                 int* __restrict__ start,
                                                 int* __restrict__ cursor,
                                                 float* __restrict__ dinv, int n) {
    __shared__ int s[SCAN_TILE];
    int tid = threadIdx.x;
    int i = blockIdx.x * SCAN_TILE + tid;
    int v = (i < n) ? deg[i] : 0;
    s[tid] = v;
    __syncthreads();
    for (int off = 1; off < SCAN_TILE; off <<= 1) {
        int t = (tid >= off) ? s[tid - off] : 0;
        __syncthreads();
        s[tid] += t;
        __syncthreads();
    }
    if (i < n) {
        int ex = boff[blockIdx.x] + s[tid] - v;
        start[i] = ex;
        cursor[i] = ex;
        dinv[i] = rsqrtf((float)(v + 1));
    }
}

// ---------------------------------------------------------------- CSR fill: src index only
__global__ void k_fill(const int* __restrict__ src, const int* __restrict__ dst,
                       int* __restrict__ cursor, int* __restrict__ csr_src, int E) {
    int e4 = (blockIdx.x * blockDim.x + threadIdx.x) << 2;
    if (e4 + 4 <= E) {
        int4 s = *(const int4*)&src[e4];
        int4 d = *(const int4*)&dst[e4];
        csr_src[atomicAdd(&cursor[d.x], 1)] = s.x;
        csr_src[atomicAdd(&cursor[d.y], 1)] = s.y;
        csr_src[atomicAdd(&cursor[d.z], 1)] = s.z;
        csr_src[atomicAdd(&cursor[d.w], 1)] = s.w;
    } else {
        for (int e = e4; e < E; ++e)
            csr_src[atomicAdd(&cursor[dst[e]], 1)] = src[e];
    }
}

// ---------------------------------------------------------------- graph boundaries
__global__ void k_bounds(const int* __restrict__ batch, int* __restrict__ goff, int n) {
    int g = threadIdx.x;
    if (g > N_GRAPHS) return;
    int lo = 0, hi = n;
    while (lo < hi) {
        int m = (lo + hi) >> 1;
        if (batch[m] < g) lo = m + 1; else hi = m;
    }
    goff[g] = lo;
}

// ---------------------------------------------------------------- prep: xp = dinv*x (pad 8)
__global__ void k_prep(const float* __restrict__ x, const float* __restrict__ dinv,
                       float* __restrict__ xp, int n) {
    int t = blockIdx.x * blockDim.x + threadIdx.x;
    int i = t >> 3, j = t & 7;
    if (i >= n) return;
    xp[t] = (j < N_FEAT) ? dinv[i] * x[i * N_FEAT + j] : 0.f;
}

// ---------------------------------------------------------------- layer-1 aggregation on 7-dim (L2-resident)
__global__ __launch_bounds__(256) void k_agg7(const float* __restrict__ xp,
                                              float* __restrict__ ax,
                                              const int* __restrict__ start,
                                              const int* __restrict__ csr_src,
                                              const float* __restrict__ dinv, int nnodes) {
    int t = blockIdx.x * blockDim.x + threadIdx.x;
    int g = t >> 3, j = t & 7;
    if (g >= nnodes) return;
    float acc = xp[(size_t)g * 8 + j];
    int e0 = start[g], e1 = start[g + 1];
    int e = e0;
    for (; e + 4 <= e1; e += 4) {
        int s0 = csr_src[e + 0], s1 = csr_src[e + 1];
        int s2 = csr_src[e + 2], s3 = csr_src[e + 3];
        acc += xp[(size_t)s0 * 8 + j] + xp[(size_t)s1 * 8 + j]
             + xp[(size_t)s2 * 8 + j] + xp[(size_t)s3 * 8 + j];
    }
    for (; e < e1; ++e) acc += xp[(size_t)csr_src[e] * 8 + j];
    ax[(size_t)g * 8 + j] = dinv[g] * acc;
}

// ---------------------------------------------------------------- layer-1 transform: h1 = relu(ax @ W1 + b1)
__global__ __launch_bounds__(256) void k_gemm7(const float* __restrict__ AX,
                                               const float* __restrict__ W1,
                                               const float* __restrict__ b1,
                                               float* __restrict__ h1, int n) {
    __shared__ float w[N_FEAT * HIDDEN];
    __shared__ float bs[HIDDEN];
    int tid = threadIdx.x;
    for (int i = tid; i < N_FEAT * HIDDEN; i += 256) w[i] = W1[i];
    if (tid < HIDDEN) bs[tid] = b1[tid];
    __syncthreads();
    int row = blockIdx.x * 2 + (tid >> 7);
    int col = tid & 127;
    if (row >= n) return;
    float acc = bs[col];
#pragma unroll
    for (int k = 0; k < N_FEAT; ++k)
        acc += AX[(size_t)row * 8 + k] * w[k * HIDDEN + col];
    h1[(size_t)row * HIDDEN + col] = fmaxf(acc, 0.f);
}

// ---------------------------------------------------------------- dense fp32 GEMM, fp16 pre-scaled output: Ts = half(dinv*(A@W))
__global__ __launch_bounds__(256) void k_gemm128(const float* __restrict__ A,
                                                 const float* __restrict__ W,
                                                 const float* __restrict__ dinv,
                                                 __half* __restrict__ Ts, int nrows) {
    __shared__ float as[16][68];
    __shared__ float ws[16][132];
    int row0 = blockIdx.x * 64;
    int tid = threadIdx.x;
    int tr = tid >> 4;
    int tc = tid & 15;
    float acc[4][8] = {};
    for (int k0 = 0; k0 < 128; k0 += 16) {
        {
            int r = tid >> 2;
            int ko = (tid & 3) << 2;
            float4 av = make_float4(0.f, 0.f, 0.f, 0.f);
            if (row0 + r < nrows)
                av = *(const float4*)&A[(size_t)(row0 + r) * 128 + k0 + ko];
            as[ko + 0][r] = av.x; as[ko + 1][r] = av.y;
            as[ko + 2][r] = av.z; as[ko + 3][r] = av.w;
        }
        {
            int wk = tid >> 4;
            int wc = (tid & 15) << 2;
            const float* wp = &W[(size_t)(k0 + wk) * 128 + wc];
            *(float4*)&ws[wk][wc]      = *(const float4*)(wp);
            *(float4*)&ws[wk][wc + 64] = *(const float4*)(wp + 64);
        }
        __syncthreads();
#pragma unroll
        for (int kk = 0; kk < 16; ++kk) {
            float a[4], b[8];
            *(float4*)&a[0] = *(const float4*)&as[kk][tr * 4];
            *(float4*)&b[0] = *(const float4*)&ws[kk][tc * 4];
            *(float4*)&b[4] = *(const float4*)&ws[kk][64 + tc * 4];
#pragma unroll
            for (int i = 0; i < 4; ++i)
#pragma unroll
                for (int j = 0; j < 8; ++j)
                    acc[i][j] += a[i] * b[j];
        }
        __syncthreads();
    }
#pragma unroll
    for (int i = 0; i < 4; ++i) {
        int rr = row0 + tr * 4 + i;
        if (rr < nrows) {
            float sc = dinv[rr];
            __half* dstp = &Ts[(size_t)rr * 128];
            sth4(dstp + tc * 4,      sc * acc[i][0], sc * acc[i][1], sc * acc[i][2], sc * acc[i][3]);
            sth4(dstp + 64 + tc * 4, sc * acc[i][4], sc * acc[i][5], sc * acc[i][6], sc * acc[i][7]);
        }
    }
}

// ---------------------------------------------------------------- aggregation on fp16 pre-scaled Ts:
// H[i] = dinv[i] * (sum_src Ts[src] + Ts[i]) + b ; optional relu (fp32 accum/output)
__global__ __launch_bounds__(256) void k_agg(const __half* __restrict__ Ts, float* __restrict__ H,
                                             const int* __restrict__ start,
                                             const int* __restrict__ csr_src,
                                             const float* __restrict__ dinv,
                                             const float* __restrict__ bias,
                                             int relu, int nnodes) {
    int g = (blockIdx.x * blockDim.x + threadIdx.x) >> 5;
    int lane = threadIdx.x & 31;
    if (g >= nnodes) return;
    const int loff = lane * 4;
    float4 v = ldh4(&Ts[(size_t)g * 128 + loff]);   // self
    float ax = v.x, ay = v.y, az = v.z, aw = v.w;
    int e0 = start[g], e1 = start[g + 1];
    int e = e0;
    for (; e + 8 <= e1; e += 8) {
        int s[8];
        float4 u[8];
#pragma unroll
        for (int j = 0; j < 8; ++j) s[j] = csr_src[e + j];
#pragma unroll
        for (int j = 0; j < 8; ++j) u[j] = ldh4(&Ts[(size_t)s[j] * 128 + loff]);
#pragma unroll
        for (int j = 0; j < 8; ++j) {
            ax += u[j].x; ay += u[j].y; az += u[j].z; aw += u[j].w;
        }
    }
    if (e + 4 <= e1) {
        int s[4];
        float4 u[4];
#pragma unroll
        for (int j = 0; j < 4; ++j) s[j] = csr_src[e + j];
#pragma unroll
        for (int j = 0; j < 4; ++j) u[j] = ldh4(&Ts[(size_t)s[j] * 128 + loff]);
#pragma unroll
        for (int j = 0; j < 4; ++j) {
            ax += u[j].x; ay += u[j].y; az += u[j].z; aw += u[j].w;
        }
        e += 4;
    }
    for (; e < e1; ++e) {
        float4 u = ldh4(&Ts[(size_t)csr_src[e] * 128 + loff]);
        ax += u.x; ay += u.y; az += u.z; aw += u.w;
    }
    float di = dinv[g];
    float4 b = *(const float4*)&bias[loff];
    ax = di * ax + b.x; ay = di * ay + b.y;
    az = di * az + b.z; aw = di * aw + b.w;
    if (relu) {
        ax = fmaxf(ax, 0.f); ay = fmaxf(ay, 0.f);
        az = fmaxf(az, 0.f); aw = fmaxf(aw, 0.f);
    }
    *(float4*)&H[(size_t)g * 128 + loff] = make_float4(ax, ay, az, aw);
}

// ---------------------------------------------------------------- pooling: 8 blocks/graph, register accumulate + LDS reduce
__global__ __launch_bounds__(256) void k_pool2(const float* __restrict__ H,
                                               const int* __restrict__ goff,
                                               float* __restrict__ gsum) {
    int g   = blockIdx.x >> 3;          // graph
    int sub = blockIdx.x & 7;           // 0..7
    int grp = threadIdx.x >> 5;         // 0..7
    int lane = threadIdx.x & 31;
    int n0 = goff[g], n1 = goff[g + 1];
    float4 acc = make_float4(0.f, 0.f, 0.f, 0.f);
    for (int n = n0 + sub * 8 + grp; n < n1; n += 64) {
        float4 v = *(const float4*)&H[(size_t)n * 128 + lane * 4];
        acc.x += v.x; acc.y += v.y; acc.z += v.z; acc.w += v.w;
    }
    __shared__ float red[8][128];
    *(float4*)&red[grp][lane * 4] = acc;
    __syncthreads();
    if (grp == 0) {
        float4 t = *(const float4*)&red[0][lane * 4];
#pragma unroll
        for (int k = 1; k < 8; ++k) {
            float4 r = *(const float4*)&red[k][lane * 4];
            t.x += r.x; t.y += r.y; t.z += r.z; t.w += r.w;
        }
        atomicAdd(&gsum[g * HIDDEN + lane * 4 + 0], t.x);
        atomicAdd(&gsum[g * HIDDEN + lane * 4 + 1], t.y);
        atomicAdd(&gsum[g * HIDDEN + lane * 4 + 2], t.z);
        atomicAdd(&gsum[g * HIDDEN + lane * 4 + 3], t.w);
    }
}

// ---------------------------------------------------------------- final: out[64,2] = (gsum/cnt) @ Wl + bl
__global__ __launch_bounds__(128) void k_final(const float* __restrict__ gsum,
                                               const int* __restrict__ goff,
                                               const float* __restrict__ Wl,
                                               const float* __restrict__ bl,
                                               float* __restrict__ out) {
    int tid = threadIdx.x;               // 0..127
    int g = tid >> 1;
    int c = tid & 1;
    int cnt = goff[g + 1] - goff[g];
    float inv = 1.0f / (float)max(cnt, 1);
    float acc = 0.f;
#pragma unroll 8
    for (int k = 0; k < HIDDEN; ++k)
        acc += gsum[g * HIDDEN + k] * Wl[k * N_CLASSES + c];
    out[g * N_CLASSES + c] = acc * inv + bl[c];
}

// ================================================================ launch
extern "C" void kernel_launch(void* const* d_in, const int* in_sizes, int n_in,
                              void* d_out, int out_size, void* d_ws, size_t ws_size,
                              hipStream_t stream) {
    const float* x    = (const float*)d_in[0];
    const int*   ei   = (const int*)d_in[1];
    const int*   batch= (const int*)d_in[2];
    const float* W1   = (const float*)d_in[3];
    const float* b1   = (const float*)d_in[4];
    const float* W2   = (const float*)d_in[5];
    const float* b2   = (const float*)d_in[6];
    const float* W3   = (const float*)d_in[7];
    const float* b3   = (const float*)d_in[8];
    const float* Wl   = (const float*)d_in[9];
    const float* bl   = (const float*)d_in[10];
    float* out = (float*)d_out;

    const int N = in_sizes[0] / N_FEAT;        // 40000
    const int E = in_sizes[1] / 2;             // 640000
    const int* e_src = ei;
    const int* e_dst = ei + E;
    const int B = (N + SCAN_TILE - 1) / SCAN_TILE;

    // workspace carve-out (256B aligned)
    char* ws = (char*)d_ws;
    auto carve = [&](size_t bytes) -> char* {
        char* p = ws;
        ws += (bytes + 255) & ~(size_t)255;
        return p;
    };
    __half* T       = (__half*)carve((size_t)N * HIDDEN * 2);  // fp16 pre-scaled transform
    float* H        = (float*)carve((size_t)N * HIDDEN * 4);   // h1 -> h2 -> h3
    float* xp       = (float*)carve((size_t)N * 8 * 4);
    float* ax       = (float*)carve((size_t)N * 8 * 4);
    int*   deg      = (int*)  carve((size_t)N * 4);
    int*   start    = (int*)  carve((size_t)(N + 1) * 4);
    int*   cursor   = (int*)  carve((size_t)N * 4);
    float* dinv     = (float*)carve((size_t)N * 4);
    int*   csr_src  = (int*)  carve((size_t)E * 4);
    float* gsum     = (float*)carve((size_t)N_GRAPHS * HIDDEN * 4);
    int*   goff     = (int*)  carve((size_t)(N_GRAPHS + 1) * 4);
    int*   bsum     = (int*)  carve((size_t)B * 4);
    int*   boff     = (int*)  carve((size_t)B * 4);
    if ((size_t)(ws - (char*)d_ws) > ws_size) return;

    // --- CSR build + graph bounds ---
    k_zero  <<<(N + 255) / 256, 256, 0, stream>>>(deg, gsum, N);
    k_count <<<(E / 4 + 255) / 256, 256, 0, stream>>>(e_dst, deg, E);
    k_scan_a<<<B, 1024, 0, stream>>>(deg, bsum, N);
    k_scan_b<<<1, 1024, 0, stream>>>(bsum, boff, start, B, N);
    k_scan_c<<<B, 1024, 0, stream>>>(deg, boff, start, cursor, dinv, N);
    k_fill  <<<(E / 4 + 255) / 256, 256, 0, stream>>>(e_src, e_dst, cursor, csr_src, E);
    k_bounds<<<1, 128, 0, stream>>>(batch, goff, N);

    const int aggBlocks  = (N * 32 + 255) / 256;
    const int gemmBlocks = (N + 63) / 64;

    // --- layer 1: aggregate 7-dim, then transform ---
    k_prep <<<(N * 8 + 255) / 256, 256, 0, stream>>>(x, dinv, xp, N);
    k_agg7 <<<(N * 8 + 255) / 256, 256, 0, stream>>>(xp, ax, start, csr_src, dinv, N);
    k_gemm7<<<(N + 1) / 2, 256, 0, stream>>>(ax, W1, b1, H, N);   // H = h1
    // --- layer 2 ---
    k_gemm128<<<gemmBlocks, 256, 0, stream>>>(H, W2, dinv, T, N); // T = half(dinv*(h1@W2))
    k_agg    <<<aggBlocks, 256, 0, stream>>>(T, H, start, csr_src, dinv, b2, 1, N);  // H = h2
    // --- layer 3 (no relu) ---
    k_gemm128<<<gemmBlocks, 256, 0, stream>>>(H, W3, dinv, T, N);
    k_agg    <<<aggBlocks, 256, 0, stream>>>(T, H, start, csr_src, dinv, b3, 0, N);  // H = h3
    // --- pool + classifier ---
    k_pool2<<<N_GRAPHS * 8, 256, 0, stream>>>(H, goff, gsum);
    k_final<<<1, 128, 0, stream>>>(gsum, goff, Wl, bl, out);
}

// Round 14
// 195.573 us; speedup vs baseline: 2.1910x; 1.1288x over previous
//
#include <hip/hip_runtime.h>
#include <hip/hip_bf16.h>
#include <hip/hip_fp16.h>

#define N_FEAT 7
#define HIDDEN 128
#define N_CLASSES 2
#define N_GRAPHS 64
#define SCAN_TILE 1024

typedef _Float16 half8 __attribute__((ext_vector_type(8)));
typedef float f32x4 __attribute__((ext_vector_type(4)));

// ---------------------------------------------------------------- fp16 helpers
__device__ __forceinline__ float4 ldh4(const __half* p) {
    uint2 v = *(const uint2*)p;
    __half2 a = *reinterpret_cast<__half2*>(&v.x);
    __half2 b = *reinterpret_cast<__half2*>(&v.y);
    float2 fa = __half22float2(a), fb = __half22float2(b);
    return make_float4(fa.x, fa.y, fb.x, fb.y);
}
__device__ __forceinline__ void sth4(__half* p, float a, float b, float c, float d) {
    __half2 lo = __floats2half2_rn(a, b);
    __half2 hi = __floats2half2_rn(c, d);
    uint2 v;
    v.x = *reinterpret_cast<unsigned int*>(&lo);
    v.y = *reinterpret_cast<unsigned int*>(&hi);
    *(uint2*)p = v;
}

// ---------------------------------------------------------------- zero init
__global__ void k_zero(int* __restrict__ deg, float* __restrict__ gsum, int n) {
    int i = blockIdx.x * blockDim.x + threadIdx.x;
    if (i < n) deg[i] = 0;
    if (i < N_GRAPHS * HIDDEN) gsum[i] = 0.f;
}

// ---------------------------------------------------------------- degree count (4 edges/thread)
__global__ void k_count(const int* __restrict__ dst, int* __restrict__ deg, int E) {
    int e4 = (blockIdx.x * blockDim.x + threadIdx.x) << 2;
    if (e4 + 4 <= E) {
        int4 d = *(const int4*)&dst[e4];
        atomicAdd(&deg[d.x], 1);
        atomicAdd(&deg[d.y], 1);
        atomicAdd(&deg[d.z], 1);
        atomicAdd(&deg[d.w], 1);
    } else {
        for (int e = e4; e < E; ++e) atomicAdd(&deg[dst[e]], 1);
    }
}

// ---------------------------------------------------------------- scan phase A
__global__ __launch_bounds__(1024) void k_scan_a(const int* __restrict__ deg,
                                                 int* __restrict__ bsum, int n) {
    __shared__ int s[SCAN_TILE];
    int tid = threadIdx.x;
    int i = blockIdx.x * SCAN_TILE + tid;
    s[tid] = (i < n) ? deg[i] : 0;
    __syncthreads();
#pragma unroll
    for (int off = 512; off > 0; off >>= 1) {
        if (tid < off) s[tid] += s[tid + off];
        __syncthreads();
    }
    if (tid == 0) bsum[blockIdx.x] = s[0];
}

// ---------------------------------------------------------------- scan phase B (1 block) + graph bounds fused
__global__ __launch_bounds__(1024) void k_scan_b(const int* __restrict__ bsum,
                                                 int* __restrict__ boff,
                                                 int* __restrict__ start,
                                                 const int* __restrict__ batch,
                                                 int* __restrict__ goff, int B, int n) {
    __shared__ int s[SCAN_TILE];
    int tid = threadIdx.x;
    int v = (tid < B) ? bsum[tid] : 0;
    s[tid] = v;
    __syncthreads();
    for (int off = 1; off < SCAN_TILE; off <<= 1) {
        int t = (tid >= off) ? s[tid - off] : 0;
        __syncthreads();
        s[tid] += t;
        __syncthreads();
    }
    if (tid < B) boff[tid] = s[tid] - v;
    if (tid == B - 1) start[n] = s[tid];
    // fused k_bounds: goff[g] = lower_bound(batch, g)
    if (tid <= N_GRAPHS) {
        int lo = 0, hi = n;
        while (lo < hi) {
            int m = (lo + hi) >> 1;
            if (batch[m] < tid) lo = m + 1; else hi = m;
        }
        goff[tid] = lo;
    }
}

// ---------------------------------------------------------------- scan phase C + prep fused (xp = dinv*x, pad 8)
__global__ __launch_bounds__(1024) void k_scan_c(const int* __restrict__ deg,
                                                 const int* __restrict__ boff,
                                                 int* __restrict__ start,
                                                 int* __restrict__ cursor,
                                                 float* __restrict__ dinv,
                                                 const float* __restrict__ x,
                                                 float* __restrict__ xp, int n) {
    __shared__ int s[SCAN_TILE];
    int tid = threadIdx.x;
    int i = blockIdx.x * SCAN_TILE + tid;
    int v = (i < n) ? deg[i] : 0;
    s[tid] = v;
    __syncthreads();
    for (int off = 1; off < SCAN_TILE; off <<= 1) {
        int t = (tid >= off) ? s[tid - off] : 0;
        __syncthreads();
        s[tid] += t;
        __syncthreads();
    }
    if (i < n) {
        int ex = boff[blockIdx.x] + s[tid] - v;
        start[i] = ex;
        cursor[i] = ex;
        float di = rsqrtf((float)(v + 1));
        dinv[i] = di;
#pragma unroll
        for (int j = 0; j < 8; ++j)
            xp[(size_t)i * 8 + j] = (j < N_FEAT) ? di * x[i * N_FEAT + j] : 0.f;
    }
}

// ---------------------------------------------------------------- CSR fill: src index only
__global__ void k_fill(const int* __restrict__ src, const int* __restrict__ dst,
                       int* __restrict__ cursor, int* __restrict__ csr_src, int E) {
    int e4 = (blockIdx.x * blockDim.x + threadIdx.x) << 2;
    if (e4 + 4 <= E) {
        int4 s = *(const int4*)&src[e4];
        int4 d = *(const int4*)&dst[e4];
        csr_src[atomicAdd(&cursor[d.x], 1)] = s.x;
        csr_src[atomicAdd(&cursor[d.y], 1)] = s.y;
        csr_src[atomicAdd(&cursor[d.z], 1)] = s.z;
        csr_src[atomicAdd(&cursor[d.w], 1)] = s.w;
    } else {
        for (int e = e4; e < E; ++e)
            csr_src[atomicAdd(&cursor[dst[e]], 1)] = src[e];
    }
}

// ---------------------------------------------------------------- W pre-pack to MFMA fragment order (fp16):
// Whp[c*2048 + kk*512 + l*8 + j] = W[(kk*32 + (l>>4)*8 + j)*128 + c*16 + (l&15)]
__global__ void k_wpack(const float* __restrict__ W2, const float* __restrict__ W3,
                        __half* __restrict__ Whp2, __half* __restrict__ Whp3) {
    int idx = blockIdx.x * blockDim.x + threadIdx.x;   // 0..32767
    int sel = idx >> 14;
    int e = idx & 16383;
    int j = e & 7, l = (e >> 3) & 63, kk = (e >> 9) & 3, c = e >> 11;
    int k = kk * 32 + (l >> 4) * 8 + j;
    int col = c * 16 + (l & 15);
    const float* W = sel ? W3 : W2;
    __half* O = sel ? Whp3 : Whp2;
    O[e] = __float2half(W[k * 128 + col]);
}

// ---------------------------------------------------------------- layer-1 aggregation on 7-dim (L2-resident)
__global__ __launch_bounds__(256) void k_agg7(const float* __restrict__ xp,
                                              float* __restrict__ ax,
                                              const int* __restrict__ start,
                                              const int* __restrict__ csr_src,
                                              const float* __restrict__ dinv, int nnodes) {
    int t = blockIdx.x * blockDim.x + threadIdx.x;
    int g = t >> 3, j = t & 7;
    if (g >= nnodes) return;
    float acc = xp[(size_t)g * 8 + j];
    int e0 = start[g], e1 = start[g + 1];
    int e = e0;
    for (; e + 4 <= e1; e += 4) {
        int s0 = csr_src[e + 0], s1 = csr_src[e + 1];
        int s2 = csr_src[e + 2], s3 = csr_src[e + 3];
        acc += xp[(size_t)s0 * 8 + j] + xp[(size_t)s1 * 8 + j]
             + xp[(size_t)s2 * 8 + j] + xp[(size_t)s3 * 8 + j];
    }
    for (; e < e1; ++e) acc += xp[(size_t)csr_src[e] * 8 + j];
    ax[(size_t)g * 8 + j] = dinv[g] * acc;
}

// ---------------------------------------------------------------- layer-1 transform: h1 = relu(ax @ W1 + b1) -> fp16
__global__ __launch_bounds__(256) void k_gemm7(const float* __restrict__ AX,
                                               const float* __restrict__ W1,
                                               const float* __restrict__ b1,
                                               __half* __restrict__ h1, int n) {
    __shared__ float w[N_FEAT * HIDDEN];
    __shared__ float bs[HIDDEN];
    int tid = threadIdx.x;
    for (int i = tid; i < N_FEAT * HIDDEN; i += 256) w[i] = W1[i];
    if (tid < HIDDEN) bs[tid] = b1[tid];
    __syncthreads();
    int row = blockIdx.x * 2 + (tid >> 7);
    int col = tid & 127;
    if (row >= n) return;
    float acc = bs[col];
#pragma unroll
    for (int k = 0; k < N_FEAT; ++k)
        acc += AX[(size_t)row * 8 + k] * w[k * HIDDEN + col];
    h1[(size_t)row * HIDDEN + col] = __float2half(fmaxf(acc, 0.f));
}

// ---------------------------------------------------------------- MFMA GEMM: Ts = half(dinv * (A16 @ W)), A16 fp16 [n,128]
// 4 waves/block, 64 rows/block. Wave w: rows w*16..+15, all 128 cols (8 col-tiles).
// mfma_f32_16x16x32_f16; A from row-major H16, B from pre-packed Whp.
__global__ __launch_bounds__(256) void k_gemm128m(const __half* __restrict__ A16,
                                                  const __half* __restrict__ Whp,
                                                  const float* __restrict__ dinv,
                                                  __half* __restrict__ Ts, int nrows) {
    __shared__ __half ctile[64][128];
    int tid = threadIdx.x;
    int w = tid >> 6;
    int lane = tid & 63;
    int row0 = blockIdx.x * 64;
    int m = lane & 15;         // A row within 16-tile / C col within 16-tile
    int kg = lane >> 4;        // k-group 0..3
    f32x4 acc[8];
#pragma unroll
    for (int c = 0; c < 8; ++c) acc[c] = (f32x4){0.f, 0.f, 0.f, 0.f};
    int arow = row0 + w * 16 + m;
#pragma unroll
    for (int kk = 0; kk < 4; ++kk) {
        uint4 av = make_uint4(0u, 0u, 0u, 0u);
        if (arow < nrows)
            av = *(const uint4*)&A16[(size_t)arow * 128 + kk * 32 + kg * 8];
        half8 a = *reinterpret_cast<half8*>(&av);
#pragma unroll
        for (int c = 0; c < 8; ++c) {
            uint4 bv = *(const uint4*)&Whp[((c * 4 + kk) << 9) + lane * 8];
            half8 b = *reinterpret_cast<half8*>(&bv);
            acc[c] = __builtin_amdgcn_mfma_f32_16x16x32_f16(a, b, acc[c], 0, 0, 0);
        }
    }
    // epilogue: C layout col=lane&15, row=(lane>>4)*4+reg  [verified m89]
    int crow = w * 16 + kg * 4;
#pragma unroll
    for (int reg = 0; reg < 4; ++reg) {
        int rr = row0 + crow + reg;
        float sc = (rr < nrows) ? dinv[rr] : 0.f;
#pragma unroll
        for (int c = 0; c < 8; ++c)
            ctile[crow + reg][c * 16 + m] = __float2half(sc * acc[c][reg]);
    }
    __syncthreads();
    const uint4* srcp = (const uint4*)&ctile[0][0];
    uint4* dstp = (uint4*)&Ts[(size_t)row0 * 128];
#pragma unroll
    for (int r = 0; r < 4; ++r) {
        int idx = r * 256 + tid;          // 1024 uint4 = 64 rows * 16/row
        if (row0 + (idx >> 4) < nrows) dstp[idx] = srcp[idx];
    }
}

// ---------------------------------------------------------------- aggregation on fp16 pre-scaled Ts:
// H[i] = dinv[i]*(sum_src Ts[src] + Ts[i]) + b ; OUT16: fp16 output (GEMM input), else fp32 (pool input)
template<int OUT16>
__global__ __launch_bounds__(256) void k_agg(const __half* __restrict__ Ts,
                                             float* __restrict__ H32,
                                             __half* __restrict__ H16o,
                                             const int* __restrict__ start,
                                             const int* __restrict__ csr_src,
                                             const float* __restrict__ dinv,
                                             const float* __restrict__ bias,
                                             int relu, int nnodes) {
    int g = (blockIdx.x * blockDim.x + threadIdx.x) >> 5;
    int lane = threadIdx.x & 31;
    if (g >= nnodes) return;
    const int loff = lane * 4;
    float4 v = ldh4(&Ts[(size_t)g * 128 + loff]);   // self
    float ax = v.x, ay = v.y, az = v.z, aw = v.w;
    int e0 = start[g], e1 = start[g + 1];
    int e = e0;
    for (; e + 8 <= e1; e += 8) {
        int s[8];
        float4 u[8];
#pragma unroll
        for (int j = 0; j < 8; ++j) s[j] = csr_src[e + j];
#pragma unroll
        for (int j = 0; j < 8; ++j) u[j] = ldh4(&Ts[(size_t)s[j] * 128 + loff]);
#pragma unroll
        for (int j = 0; j < 8; ++j) {
            ax += u[j].x; ay += u[j].y; az += u[j].z; aw += u[j].w;
        }
    }
    if (e + 4 <= e1) {
        int s[4];
        float4 u[4];
#pragma unroll
        for (int j = 0; j < 4; ++j) s[j] = csr_src[e + j];
#pragma unroll
        for (int j = 0; j < 4; ++j) u[j] = ldh4(&Ts[(size_t)s[j] * 128 + loff]);
#pragma unroll
        for (int j = 0; j < 4; ++j) {
            ax += u[j].x; ay += u[j].y; az += u[j].z; aw += u[j].w;
        }
        e += 4;
    }
    for (; e < e1; ++e) {
        float4 u = ldh4(&Ts[(size_t)csr_src[e] * 128 + loff]);
        ax += u.x; ay += u.y; az += u.z; aw += u.w;
    }
    float di = dinv[g];
    float4 b = *(const float4*)&bias[loff];
    ax = di * ax + b.x; ay = di * ay + b.y;
    az = di * az + b.z; aw = di * aw + b.w;
    if (relu) {
        ax = fmaxf(ax, 0.f); ay = fmaxf(ay, 0.f);
        az = fmaxf(az, 0.f); aw = fmaxf(aw, 0.f);
    }
    if (OUT16) {
        sth4(&H16o[(size_t)g * 128 + loff], ax, ay, az, aw);
    } else {
        *(float4*)&H32[(size_t)g * 128 + loff] = make_float4(ax, ay, az, aw);
    }
}

// ---------------------------------------------------------------- pooling: 8 blocks/graph, register accumulate + LDS reduce
__global__ __launch_bounds__(256) void k_pool2(const float* __restrict__ H,
                                               const int* __restrict__ goff,
                                               float* __restrict__ gsum) {
    int g   = blockIdx.x >> 3;
    int sub = blockIdx.x & 7;
    int grp = threadIdx.x >> 5;
    int lane = threadIdx.x & 31;
    int n0 = goff[g], n1 = goff[g + 1];
    float4 acc = make_float4(0.f, 0.f, 0.f, 0.f);
    for (int n = n0 + sub * 8 + grp; n < n1; n += 64) {
        float4 v = *(const float4*)&H[(size_t)n * 128 + lane * 4];
        acc.x += v.x; acc.y += v.y; acc.z += v.z; acc.w += v.w;
    }
    __shared__ float red[8][128];
    *(float4*)&red[grp][lane * 4] = acc;
    __syncthreads();
    if (grp == 0) {
        float4 t = *(const float4*)&red[0][lane * 4];
#pragma unroll
        for (int k = 1; k < 8; ++k) {
            float4 r = *(const float4*)&red[k][lane * 4];
            t.x += r.x; t.y += r.y; t.z += r.z; t.w += r.w;
        }
        atomicAdd(&gsum[g * HIDDEN + lane * 4 + 0], t.x);
        atomicAdd(&gsum[g * HIDDEN + lane * 4 + 1], t.y);
        atomicAdd(&gsum[g * HIDDEN + lane * 4 + 2], t.z);
        atomicAdd(&gsum[g * HIDDEN + lane * 4 + 3], t.w);
    }
}

// ---------------------------------------------------------------- final: out[64,2] = (gsum/cnt) @ Wl + bl
__global__ __launch_bounds__(128) void k_final(const float* __restrict__ gsum,
                                               const int* __restrict__ goff,
                                               const float* __restrict__ Wl,
                                               const float* __restrict__ bl,
                                               float* __restrict__ out) {
    int tid = threadIdx.x;
    int g = tid >> 1;
    int c = tid & 1;
    int cnt = goff[g + 1] - goff[g];
    float inv = 1.0f / (float)max(cnt, 1);
    float acc = 0.f;
#pragma unroll 8
    for (int k = 0; k < HIDDEN; ++k)
        acc += gsum[g * HIDDEN + k] * Wl[k * N_CLASSES + c];
    out[g * N_CLASSES + c] = acc * inv + bl[c];
}

// ================================================================ launch
extern "C" void kernel_launch(void* const* d_in, const int* in_sizes, int n_in,
                              void* d_out, int out_size, void* d_ws, size_t ws_size,
                              hipStream_t stream) {
    const float* x    = (const float*)d_in[0];
    const int*   ei   = (const int*)d_in[1];
    const int*   batch= (const int*)d_in[2];
    const float* W1   = (const float*)d_in[3];
    const float* b1   = (const float*)d_in[4];
    const float* W2   = (const float*)d_in[5];
    const float* b2   = (const float*)d_in[6];
    const float* W3   = (const float*)d_in[7];
    const float* b3   = (const float*)d_in[8];
    const float* Wl   = (const float*)d_in[9];
    const float* bl   = (const float*)d_in[10];
    float* out = (float*)d_out;

    const int N = in_sizes[0] / N_FEAT;        // 40000
    const int E = in_sizes[1] / 2;             // 640000
    const int* e_src = ei;
    const int* e_dst = ei + E;
    const int B = (N + SCAN_TILE - 1) / SCAN_TILE;

    // workspace carve-out (256B aligned)
    char* ws = (char*)d_ws;
    auto carve = [&](size_t bytes) -> char* {
        char* p = ws;
        ws += (bytes + 255) & ~(size_t)255;
        return p;
    };
    __half* T       = (__half*)carve((size_t)N * HIDDEN * 2);  // fp16 pre-scaled transform
    __half* H16     = (__half*)carve((size_t)N * HIDDEN * 2);  // h1 -> h2 (GEMM inputs)
    float*  H32     = (float*) carve((size_t)N * HIDDEN * 4);  // h3 (pool input)
    float*  xp      = (float*) carve((size_t)N * 8 * 4);
    float*  ax      = (float*) carve((size_t)N * 8 * 4);
    int*    deg     = (int*)   carve((size_t)N * 4);
    int*    start   = (int*)   carve((size_t)(N + 1) * 4);
    int*    cursor  = (int*)   carve((size_t)N * 4);
    float*  dinv    = (float*) carve((size_t)N * 4);
    int*    csr_src = (int*)   carve((size_t)E * 4);
    float*  gsum    = (float*) carve((size_t)N_GRAPHS * HIDDEN * 4);
    int*    goff    = (int*)   carve((size_t)(N_GRAPHS + 1) * 4);
    int*    bsum    = (int*)   carve((size_t)B * 4);
    int*    boff    = (int*)   carve((size_t)B * 4);
    __half* Whp2    = (__half*)carve((size_t)HIDDEN * HIDDEN * 2);
    __half* Whp3    = (__half*)carve((size_t)HIDDEN * HIDDEN * 2);
    if ((size_t)(ws - (char*)d_ws) > ws_size) return;

    // --- CSR build (+bounds, +prep fused) + W pre-pack ---
    k_zero  <<<(N + 255) / 256, 256, 0, stream>>>(deg, gsum, N);
    k_count <<<(E / 4 + 255) / 256, 256, 0, stream>>>(e_dst, deg, E);
    k_wpack <<<(2 * HIDDEN * HIDDEN + 255) / 256, 256, 0, stream>>>(W2, W3, Whp2, Whp3);
    k_scan_a<<<B, 1024, 0, stream>>>(deg, bsum, N);
    k_scan_b<<<1, 1024, 0, stream>>>(bsum, boff, start, batch, goff, B, N);
    k_scan_c<<<B, 1024, 0, stream>>>(deg, boff, start, cursor, dinv, x, xp, N);
    k_fill  <<<(E / 4 + 255) / 256, 256, 0, stream>>>(e_src, e_dst, cursor, csr_src, E);

    const int aggBlocks  = (N * 32 + 255) / 256;
    const int gemmBlocks = (N + 63) / 64;

    // --- layer 1: aggregate 7-dim, then transform ---
    k_agg7 <<<(N * 8 + 255) / 256, 256, 0, stream>>>(xp, ax, start, csr_src, dinv, N);
    k_gemm7<<<(N + 1) / 2, 256, 0, stream>>>(ax, W1, b1, H16, N);          // H16 = h1 (fp16)
    // --- layer 2 ---
    k_gemm128m<<<gemmBlocks, 256, 0, stream>>>(H16, Whp2, dinv, T, N);     // T = half(dinv*(h1@W2))
    k_agg<1>  <<<aggBlocks, 256, 0, stream>>>(T, nullptr, H16, start, csr_src, dinv, b2, 1, N);  // H16 = h2
    // --- layer 3 (no relu) ---
    k_gemm128m<<<gemmBlocks, 256, 0, stream>>>(H16, Whp3, dinv, T, N);
    k_agg<0>  <<<aggBlocks, 256, 0, stream>>>(T, H32, nullptr, start, csr_src, dinv, b3, 0, N);  // H32 = h3
    // --- pool + classifier ---
    k_pool2<<<N_GRAPHS * 8, 256, 0, stream>>>(H32, goff, gsum);
    k_final<<<1, 128, 0, stream>>>(gsum, goff, Wl, bl, out);
}